// Round 1
// baseline (2057.660 us; speedup 1.0000x reference)
//
#include <hip/hip_runtime.h>
#include <math.h>

#define BSZ 4
#define SEQ 2048
#define DIMN 1024
#define NHEAD 16
#define DHEAD 64
#define MROWS (BSZ*SEQ)   // 8192

// ---------------------------------------------------------------------------
// GEMM: C[M,N] = X[M,K] @ W[N,K]^T + bias[N]   (torch Linear layout)
// BM=BN=64, BK=16, 256 threads (16x16), 4x4 outputs/thread, fp32 vector FMA.
// ---------------------------------------------------------------------------
__global__ __launch_bounds__(256) void gemm_bt(
    const float* __restrict__ X, const float* __restrict__ W,
    const float* __restrict__ bias, float* __restrict__ C,
    int M, int N, int K)
{
  __shared__ __align__(16) float Xs[16][68];  // [k][m] transposed on load
  __shared__ __align__(16) float Ws[16][68];  // [k][n]
  const int t  = threadIdx.x;
  const int tx = t & 15, ty = t >> 4;
  const int m0 = blockIdx.y << 6, n0 = blockIdx.x << 6;
  const int ldr = t >> 2;            // 0..63 tile row to load
  const int lk  = (t & 3) << 2;      // 0,4,8,12 k-offset (float4)
  float acc[4][4] = {{0.f}};
  const float* Xp = X + (size_t)(m0 + ldr) * K + lk;
  const float* Wp = W + (size_t)(n0 + ldr) * K + lk;
  for (int k0 = 0; k0 < K; k0 += 16) {
    float4 xa = *(const float4*)(Xp + k0);
    float4 wa = *(const float4*)(Wp + k0);
    Xs[lk+0][ldr]=xa.x; Xs[lk+1][ldr]=xa.y; Xs[lk+2][ldr]=xa.z; Xs[lk+3][ldr]=xa.w;
    Ws[lk+0][ldr]=wa.x; Ws[lk+1][ldr]=wa.y; Ws[lk+2][ldr]=wa.z; Ws[lk+3][ldr]=wa.w;
    __syncthreads();
#pragma unroll
    for (int kk = 0; kk < 16; ++kk) {
      float4 a4 = *(const float4*)&Xs[kk][ty<<2];
      float4 b4 = *(const float4*)&Ws[kk][tx<<2];
      float av[4] = {a4.x, a4.y, a4.z, a4.w};
      float bv[4] = {b4.x, b4.y, b4.z, b4.w};
#pragma unroll
      for (int i = 0; i < 4; ++i)
#pragma unroll
        for (int j = 0; j < 4; ++j)
          acc[i][j] = fmaf(av[i], bv[j], acc[i][j]);
    }
    __syncthreads();
  }
  float4 bb4 = *(const float4*)&bias[n0 + (tx<<2)];
  const float bv[4] = {bb4.x, bb4.y, bb4.z, bb4.w};
#pragma unroll
  for (int i = 0; i < 4; ++i) {
    float4 o;
    o.x = acc[i][0]+bv[0]; o.y = acc[i][1]+bv[1];
    o.z = acc[i][2]+bv[2]; o.w = acc[i][3]+bv[3];
    *(float4*)&C[(size_t)(m0 + (ty<<2) + i) * N + n0 + (tx<<2)] = o;
  }
}

// ---------------------------------------------------------------------------
// Flash-style attention. One block = one (b,h) x 64-row Q tile.
// 256 threads (16x16): thread (tx,ty) owns rows ty*4..+3, cols tx*4..+3.
// Online softmax; P round-trips through the K LDS buffer.
// Scores scaled by 1/sqrt(DH)=0.125 (equivalent to scaling q).
// ---------------------------------------------------------------------------
__global__ __launch_bounds__(256) void attn_fwd(
    const float* __restrict__ Q, const float* __restrict__ Kbuf,
    const float* __restrict__ Vbuf, const int* __restrict__ mask,
    float* __restrict__ CTX)
{
  __shared__ __align__(16) float Qs[64][68];   // [k][qrow]
  __shared__ __align__(16) float KPs[64][68];  // K: [k][kcol]; then P: [kk][qrow]
  __shared__ __align__(16) float Vs[64][68];   // [krow][d]
  const int t  = threadIdx.x;
  const int tx = t & 15, ty = t >> 4;
  const int qt = blockIdx.x;        // 0..31
  const int bh = blockIdx.y;        // 0..63
  const int b  = bh >> 4, h = bh & 15;   // NHEAD=16
  const int ldr = t >> 2;           // 0..63
  const int lcb = (t & 3) << 2;     // 0,4,8,12

  // Load Q tile transposed: Qs[k][row]
  const float* Qp = Q + (size_t)(b*SEQ + (qt<<6)) * DIMN + h*DHEAD;
#pragma unroll
  for (int u = 0; u < 4; ++u) {
    int kb = lcb + (u<<4);
    float4 q4 = *(const float4*)(Qp + (size_t)ldr*DIMN + kb);
    Qs[kb+0][ldr]=q4.x; Qs[kb+1][ldr]=q4.y; Qs[kb+2][ldr]=q4.z; Qs[kb+3][ldr]=q4.w;
  }

  float mrow[4], lsum[4], o[4][4];
#pragma unroll
  for (int i = 0; i < 4; ++i) {
    mrow[i] = -1e30f; lsum[i] = 0.f;
#pragma unroll
    for (int j = 0; j < 4; ++j) o[i][j] = 0.f;
  }
  const int qrow0 = ty << 2;
  const int col0  = tx << 2;

  for (int kt = 0; kt < SEQ/64; ++kt) {
    __syncthreads();   // prev iter done with KPs/Vs
    const float* Kp = Kbuf + (size_t)(b*SEQ + (kt<<6)) * DIMN + h*DHEAD;
    const float* Vp = Vbuf + (size_t)(b*SEQ + (kt<<6)) * DIMN + h*DHEAD;
#pragma unroll
    for (int u = 0; u < 4; ++u) {
      int kb = lcb + (u<<4);
      float4 k4 = *(const float4*)(Kp + (size_t)ldr*DIMN + kb);
      KPs[kb+0][ldr]=k4.x; KPs[kb+1][ldr]=k4.y; KPs[kb+2][ldr]=k4.z; KPs[kb+3][ldr]=k4.w;
      float4 v4 = *(const float4*)(Vp + (size_t)ldr*DIMN + kb);
      *(float4*)&Vs[ldr][kb] = v4;
    }
    __syncthreads();

    // S = Q @ K^T  (64x64, k=64)
    float s[4][4] = {{0.f}};
#pragma unroll 8
    for (int kk = 0; kk < 64; ++kk) {
      float4 a4 = *(const float4*)&Qs[kk][qrow0];
      float4 b4 = *(const float4*)&KPs[kk][col0];
      float av[4] = {a4.x, a4.y, a4.z, a4.w};
      float bv[4] = {b4.x, b4.y, b4.z, b4.w};
#pragma unroll
      for (int i = 0; i < 4; ++i)
#pragma unroll
        for (int j = 0; j < 4; ++j)
          s[i][j] = fmaf(av[i], bv[j], s[i][j]);
    }

    // mask + scale + online softmax (row groups = 16 contiguous lanes)
    int mk[4];
#pragma unroll
    for (int j = 0; j < 4; ++j) mk[j] = mask[b*SEQ + (kt<<6) + col0 + j];
    float p[4][4];
#pragma unroll
    for (int i = 0; i < 4; ++i) {
#pragma unroll
      for (int j = 0; j < 4; ++j)
        s[i][j] = mk[j] ? s[i][j]*0.125f : -1e30f;
      float tm = fmaxf(fmaxf(s[i][0], s[i][1]), fmaxf(s[i][2], s[i][3]));
#pragma unroll
      for (int off = 8; off >= 1; off >>= 1)
        tm = fmaxf(tm, __shfl_xor(tm, off, 64));
      float mnew  = fmaxf(mrow[i], tm);
      float alpha = __expf(mrow[i] - mnew);
      mrow[i] = mnew;
      float rs = 0.f;
#pragma unroll
      for (int j = 0; j < 4; ++j) {
        float pv = __expf(s[i][j] - mnew);
        p[i][j] = pv; rs += pv;
      }
#pragma unroll
      for (int off = 8; off >= 1; off >>= 1)
        rs += __shfl_xor(rs, off, 64);
      lsum[i] = lsum[i]*alpha + rs;
#pragma unroll
      for (int j = 0; j < 4; ++j) o[i][j] *= alpha;
    }

    __syncthreads();   // everyone done reading KPs as K
    // write P transposed: KPs[kk][qrow]
#pragma unroll
    for (int i = 0; i < 4; ++i)
#pragma unroll
      for (int j = 0; j < 4; ++j)
        KPs[col0 + j][qrow0 + i] = p[i][j];
    __syncthreads();

    // O += P @ V
#pragma unroll 8
    for (int kk = 0; kk < 64; ++kk) {
      float4 a4 = *(const float4*)&KPs[kk][qrow0];
      float4 v4 = *(const float4*)&Vs[kk][col0];
      float av[4] = {a4.x, a4.y, a4.z, a4.w};
      float vv[4] = {v4.x, v4.y, v4.z, v4.w};
#pragma unroll
      for (int i = 0; i < 4; ++i)
#pragma unroll
        for (int j = 0; j < 4; ++j)
          o[i][j] = fmaf(av[i], vv[j], o[i][j]);
    }
  }

  // epilogue: normalize, write context in (b, s, h*DH + d) layout
  float* Cp = CTX + (size_t)(b*SEQ + (qt<<6)) * DIMN + h*DHEAD;
#pragma unroll
  for (int i = 0; i < 4; ++i) {
    float inv = lsum[i] > 0.f ? 1.0f/lsum[i] : 0.f;
    float4 ov;
    ov.x = o[i][0]*inv; ov.y = o[i][1]*inv;
    ov.z = o[i][2]*inv; ov.w = o[i][3]*inv;
    *(float4*)(Cp + (size_t)(qrow0 + i)*DIMN + col0) = ov;
  }
}

// ---------------------------------------------------------------------------
extern "C" void kernel_launch(void* const* d_in, const int* in_sizes, int n_in,
                              void* d_out, int out_size, void* d_ws, size_t ws_size,
                              hipStream_t stream)
{
  const float* query = (const float*)d_in[0];
  const float* key   = (const float*)d_in[1];
  const float* value = (const float*)d_in[2];
  const int*   mask  = (const int*)d_in[3];
  const float* Wq = (const float*)d_in[4];
  const float* bq = (const float*)d_in[5];
  const float* Wk = (const float*)d_in[6];
  const float* bk = (const float*)d_in[7];
  const float* Wv = (const float*)d_in[8];
  const float* bv = (const float*)d_in[9];
  const float* Wo = (const float*)d_in[10];
  const float* bo = (const float*)d_in[11];
  float* out = (float*)d_out;

  const size_t n = (size_t)MROWS * DIMN;
  float* Qb = (float*)d_ws;        // 32 MB
  float* Kb = Qb + n;              // 32 MB
  float* Vb = Kb + n;              // 32 MB
  float* Cb = Vb + n;              // 32 MB  (total 128 MB of d_ws)

  dim3 gg(DIMN/64, MROWS/64), blk(256);
  hipLaunchKernelGGL(gemm_bt, gg, blk, 0, stream, query, Wq, bq, Qb, MROWS, DIMN, DIMN);
  hipLaunchKernelGGL(gemm_bt, gg, blk, 0, stream, key,   Wk, bk, Kb, MROWS, DIMN, DIMN);
  hipLaunchKernelGGL(gemm_bt, gg, blk, 0, stream, value, Wv, bv, Vb, MROWS, DIMN, DIMN);

  dim3 ga(SEQ/64, BSZ*NHEAD);
  hipLaunchKernelGGL(attn_fwd, ga, blk, 0, stream, Qb, Kb, Vb, mask, Cb);

  hipLaunchKernelGGL(gemm_bt, gg, blk, 0, stream, Cb, Wo, bo, out, MROWS, DIMN, DIMN);
}

// Round 2
// 681.236 us; speedup vs baseline: 3.0205x; 3.0205x over previous
//
#include <hip/hip_runtime.h>
#include <hip/hip_bf16.h>
#include <math.h>

#define BSZ 4
#define SEQ 2048
#define DIMN 1024
#define NHEAD 16
#define DHEAD 64
#define MROWS (BSZ*SEQ)   // 8192

typedef __bf16 bf16x8 __attribute__((ext_vector_type(8)));
typedef float  f32x4  __attribute__((ext_vector_type(4)));
typedef float  fvec4  __attribute__((ext_vector_type(4)));
typedef short  s16x4  __attribute__((ext_vector_type(4)));
typedef short  s16x8  __attribute__((ext_vector_type(8)));

__device__ __forceinline__ short f2bf(float v) {
  __hip_bfloat16 b = __float2bfloat16(v);   // RNE
  return *reinterpret_cast<short*>(&b);
}
__device__ __forceinline__ float bf2f(short s) {
  __hip_bfloat16 b = *reinterpret_cast<__hip_bfloat16*>(&s);
  return __bfloat162float(b);
}

__device__ __forceinline__ void gld_lds16(const void* g, void* l) {
  __builtin_amdgcn_global_load_lds((const __attribute__((address_space(1))) void*)g,
                                   (__attribute__((address_space(3))) void*)l, 16, 0, 0);
}

// ---------------------------------------------------------------------------
// pack_split: fp32 -> (hi, lo) bf16 planes, optional scale. n % 1024 == 0.
// ---------------------------------------------------------------------------
__global__ __launch_bounds__(256) void pack_split(
    const float* __restrict__ x, short* __restrict__ hi, short* __restrict__ lo,
    long n, float scale)
{
  long i = ((long)blockIdx.x * 256 + threadIdx.x) * 4;
  if (i >= n) return;
  fvec4 v = *(const fvec4*)&x[i];
  s16x4 h, l;
#pragma unroll
  for (int j = 0; j < 4; ++j) {
    float vj = v[j] * scale;
    short hb = f2bf(vj);
    h[j] = hb;
    l[j] = f2bf(vj - bf2f(hb));
  }
  *(s16x4*)&hi[i] = h;
  *(s16x4*)&lo[i] = l;
}

__global__ __launch_bounds__(256) void maskbias_k(
    const int* __restrict__ mask, float* __restrict__ mb, int n)
{
  int i = blockIdx.x * 256 + threadIdx.x;
  if (i < n) mb[i] = mask[i] ? 0.f : -1e30f;
}

// ---------------------------------------------------------------------------
// Split-bf16 MFMA GEMM: C[M,N] = (Ah+Al)[M,K] @ (Bh+Bl)[N,K]^T + bias*bscale
// 128x128 tile, BK=32, 256 thr (4 waves 2x2), 16x16x32 MFMA, 3-term split.
// LDS tiles staged with global_load_lds (width 16).
// ---------------------------------------------------------------------------
__global__ __launch_bounds__(256) void gemm_sp(
    const short* __restrict__ Ah, const short* __restrict__ Al,
    const short* __restrict__ Bh, const short* __restrict__ Bl,
    const float* __restrict__ bias, float bscale,
    float* __restrict__ C, int M, int N, int K)
{
  __shared__ __align__(16) short sA[2*128*32];   // [plane][128][32] 16 KB
  __shared__ __align__(16) short sB[2*128*32];
  const int t = threadIdx.x;
  const int ln = t & 15, quad = (t & 63) >> 4, w = t >> 6;
  const int wm = w >> 1, wn = w & 1;
  const int m0 = blockIdx.y * 128, n0 = blockIdx.x * 128;
  const int lrow = t >> 2, lko = (t & 3) * 8;
  f32x4 acc[4][4];
#pragma unroll
  for (int i = 0; i < 4; ++i)
#pragma unroll
    for (int j = 0; j < 4; ++j) acc[i][j] = (f32x4){0.f,0.f,0.f,0.f};

  for (int k0 = 0; k0 < K; k0 += 32) {
    __syncthreads();
#pragma unroll
    for (int u = 0; u < 2; ++u) {
      int row = u*64 + lrow;
      gld_lds16(Ah + (size_t)(m0+row)*K + k0 + lko, sA + u*2048 + t*8);
      gld_lds16(Al + (size_t)(m0+row)*K + k0 + lko, sA + 4096 + u*2048 + t*8);
      gld_lds16(Bh + (size_t)(n0+row)*K + k0 + lko, sB + u*2048 + t*8);
      gld_lds16(Bl + (size_t)(n0+row)*K + k0 + lko, sB + 4096 + u*2048 + t*8);
    }
    __syncthreads();
    bf16x8 ah[4], al[4], bh[4], bl[4];
#pragma unroll
    for (int mt = 0; mt < 4; ++mt) {
      int r = wm*64 + mt*16 + ln;
      ah[mt] = *(bf16x8*)&sA[r*32 + quad*8];
      al[mt] = *(bf16x8*)&sA[4096 + r*32 + quad*8];
    }
#pragma unroll
    for (int nt = 0; nt < 4; ++nt) {
      int r = wn*64 + nt*16 + ln;
      bh[nt] = *(bf16x8*)&sB[r*32 + quad*8];
      bl[nt] = *(bf16x8*)&sB[4096 + r*32 + quad*8];
    }
#pragma unroll
    for (int mt = 0; mt < 4; ++mt)
#pragma unroll
      for (int nt = 0; nt < 4; ++nt) {
        acc[mt][nt] = __builtin_amdgcn_mfma_f32_16x16x32_bf16(ah[mt], bh[nt], acc[mt][nt], 0, 0, 0);
        acc[mt][nt] = __builtin_amdgcn_mfma_f32_16x16x32_bf16(ah[mt], bl[nt], acc[mt][nt], 0, 0, 0);
        acc[mt][nt] = __builtin_amdgcn_mfma_f32_16x16x32_bf16(al[mt], bh[nt], acc[mt][nt], 0, 0, 0);
      }
  }
#pragma unroll
  for (int nt = 0; nt < 4; ++nt) {
    float bv = bias[n0 + wn*64 + nt*16 + ln] * bscale;
#pragma unroll
    for (int mt = 0; mt < 4; ++mt)
#pragma unroll
      for (int r = 0; r < 4; ++r)
        C[(size_t)(m0 + wm*64 + mt*16 + quad*4 + r)*N + (n0 + wn*64 + nt*16 + ln)] =
            acc[mt][nt][r] + bv;
  }
}

// ---------------------------------------------------------------------------
// pack_vt: V fp32 [b][s][1024] -> Vt hi-plane bf16 [bh][d(64)][s(2048)]
// ---------------------------------------------------------------------------
__global__ __launch_bounds__(256) void pack_vt(
    const float* __restrict__ V, short* __restrict__ Vth)
{
  __shared__ float fs[64][68];
  const int t = threadIdx.x;
  const int st = blockIdx.x, bh = blockIdx.y;
  const int b = bh >> 4, hd = bh & 15;
  const int s0 = st * 64;
#pragma unroll
  for (int u = 0; u < 4; ++u) {
    int c = u*256 + t;
    int s = c >> 4, d4 = (c & 15) * 4;
    fvec4 v = *(const fvec4*)&V[(size_t)(b*SEQ + s0 + s)*DIMN + hd*64 + d4];
    fs[s][d4] = v[0]; fs[s][d4+1] = v[1]; fs[s][d4+2] = v[2]; fs[s][d4+3] = v[3];
  }
  __syncthreads();
#pragma unroll
  for (int u = 0; u < 2; ++u) {
    int c = u*256 + t;
    int d = c >> 3, s8 = (c & 7) * 8;
    s16x8 h;
#pragma unroll
    for (int j = 0; j < 8; ++j) h[j] = f2bf(fs[s8+j][d]);
    *(s16x8*)&Vth[((size_t)bh*64 + d)*SEQ + s0 + s8] = h;
  }
}

// ---------------------------------------------------------------------------
// Flash attention, MFMA. Block = (b,h) x 64-row Q tile; 4 waves, wave w owns
// q-group w*16..+15. Scores computed TRANSPOSED: St[kc][q] = K·Q^T so softmax
// state is per-lane (q = lane&15). Q split hi/lo, K single, P split, V single.
// P round-trips LDS (stride 72 = 144B rows: 16B aligned, 2-way banks).
// Q pre-scaled by 1/8 (folded into Wq pack). Mask as additive bias.
// ---------------------------------------------------------------------------
__global__ __launch_bounds__(256) void attn_sp(
    const short* __restrict__ Qh, const short* __restrict__ Ql,
    const short* __restrict__ Kh, const short* __restrict__ Vth,
    const float* __restrict__ mb, float* __restrict__ CTX)
{
  __shared__ __align__(16) short sQ[2*2*64*32];  // [plane][half][64 q][32 d] 16 KB
  __shared__ __align__(16) short sK[2*64*32];    // [half][64 kc][32 d]        8 KB
  __shared__ __align__(16) short sV[2*64*32];    // [half kc][64 d][32 kc]     8 KB
  __shared__ __align__(16) short sP[2*64*72];    // [plane][64 q][72]         18 KB
  const int t = threadIdx.x;
  const int ln = t & 15, quad = (t & 63) >> 4, w = t >> 6;
  // XCD-locality swizzle: same bh -> same (g&7) -> same XCD
  const int g = blockIdx.x;
  const int chunk = g >> 3, qt = chunk & 31, bh = ((chunk >> 5) << 3) + (g & 7);
  const int b = bh >> 4, hd = bh & 15;
  const int lrow = t >> 2, lko = (t & 3) * 8;

  // stage Q (once)
#pragma unroll
  for (int p = 0; p < 2; ++p) {
    const short* Qp = p ? Ql : Qh;
#pragma unroll
    for (int h = 0; h < 2; ++h)
      gld_lds16(Qp + (size_t)(b*SEQ + qt*64 + lrow)*DIMN + hd*64 + h*32 + lko,
                sQ + p*4096 + h*2048 + t*8);
  }
  __syncthreads();
  bf16x8 qh[2], ql[2];
#pragma unroll
  for (int ks = 0; ks < 2; ++ks) {
    qh[ks] = *(bf16x8*)&sQ[ks*2048 + (w*16+ln)*32 + quad*8];
    ql[ks] = *(bf16x8*)&sQ[4096 + ks*2048 + (w*16+ln)*32 + quad*8];
  }

  f32x4 o_acc[4];
#pragma unroll
  for (int nt = 0; nt < 4; ++nt) o_acc[nt] = (f32x4){0.f,0.f,0.f,0.f};
  float m_run = -1e30f, l_run = 0.f;

  for (int kt = 0; kt < SEQ/64; ++kt) {
    __syncthreads();
#pragma unroll
    for (int h = 0; h < 2; ++h) {
      gld_lds16(Kh  + (size_t)(b*SEQ + kt*64 + lrow)*DIMN + hd*64 + h*32 + lko,
                sK + h*2048 + t*8);
      gld_lds16(Vth + ((size_t)bh*64 + lrow)*SEQ + kt*64 + h*32 + lko,
                sV + h*2048 + t*8);
    }
    __syncthreads();

    // St[kc][q] = K·Q^T  (A = K rows kc, B = Q rows q)
    f32x4 sacc[4];
#pragma unroll
    for (int mt = 0; mt < 4; ++mt) sacc[mt] = (f32x4){0.f,0.f,0.f,0.f};
#pragma unroll
    for (int ks = 0; ks < 2; ++ks)
#pragma unroll
      for (int mt = 0; mt < 4; ++mt) {
        bf16x8 kf = *(bf16x8*)&sK[ks*2048 + (mt*16+ln)*32 + quad*8];
        sacc[mt] = __builtin_amdgcn_mfma_f32_16x16x32_bf16(kf, qh[ks], sacc[mt], 0, 0, 0);
        sacc[mt] = __builtin_amdgcn_mfma_f32_16x16x32_bf16(kf, ql[ks], sacc[mt], 0, 0, 0);
      }

    // mask bias + online softmax (lane owns q = w*16+ln; kc = mt*16+quad*4+r)
    float sv[4][4];
    float tmax = -1e30f;
#pragma unroll
    for (int mt = 0; mt < 4; ++mt) {
      fvec4 mbv = *(const fvec4*)&mb[b*SEQ + kt*64 + mt*16 + quad*4];
#pragma unroll
      for (int r = 0; r < 4; ++r) {
        sv[mt][r] = sacc[mt][r] + mbv[r];
        tmax = fmaxf(tmax, sv[mt][r]);
      }
    }
    tmax = fmaxf(tmax, __shfl_xor(tmax, 16));
    tmax = fmaxf(tmax, __shfl_xor(tmax, 32));
    float mnew  = fmaxf(m_run, tmax);
    float alpha = __expf(m_run - mnew);
    m_run = mnew;
    float rs = 0.f;
#pragma unroll
    for (int mt = 0; mt < 4; ++mt)
#pragma unroll
      for (int r = 0; r < 4; ++r) {
        float p = __expf(sv[mt][r] - mnew);
        sv[mt][r] = p; rs += p;
      }
    rs += __shfl_xor(rs, 16);
    rs += __shfl_xor(rs, 32);
    l_run = l_run * alpha + rs;

    // write P hi/lo to LDS (wave-private rows w*16..+15)
    const int q = w*16 + ln;
#pragma unroll
    for (int mt = 0; mt < 4; ++mt) {
      s16x4 ph, pl;
#pragma unroll
      for (int r = 0; r < 4; ++r) {
        short hb = f2bf(sv[mt][r]);
        ph[r] = hb;
        pl[r] = f2bf(sv[mt][r] - bf2f(hb));
      }
      *(s16x4*)&sP[q*72 + mt*16 + quad*4] = ph;
      *(s16x4*)&sP[4608 + q*72 + mt*16 + quad*4] = pl;
    }

    // rescale O rows (row q' = quad*4+r lives at lane q'=lane&15)
    float a4[4];
#pragma unroll
    for (int r = 0; r < 4; ++r) a4[r] = __shfl(alpha, quad*4 + r);
#pragma unroll
    for (int nt = 0; nt < 4; ++nt)
#pragma unroll
      for (int r = 0; r < 4; ++r) o_acc[nt][r] *= a4[r];

    // O += P·V   (A = P rows q, B = Vt rows d)
#pragma unroll
    for (int ks = 0; ks < 2; ++ks) {
      bf16x8 ph = *(bf16x8*)&sP[(w*16+ln)*72 + ks*32 + quad*8];
      bf16x8 pl = *(bf16x8*)&sP[4608 + (w*16+ln)*72 + ks*32 + quad*8];
#pragma unroll
      for (int nt = 0; nt < 4; ++nt) {
        bf16x8 vf = *(bf16x8*)&sV[ks*2048 + (nt*16+ln)*32 + quad*8];
        o_acc[nt] = __builtin_amdgcn_mfma_f32_16x16x32_bf16(ph, vf, o_acc[nt], 0, 0, 0);
        o_acc[nt] = __builtin_amdgcn_mfma_f32_16x16x32_bf16(pl, vf, o_acc[nt], 0, 0, 0);
      }
    }
  }

  float invl = (l_run > 0.f) ? 1.f / l_run : 0.f;
  float i4[4];
#pragma unroll
  for (int r = 0; r < 4; ++r) i4[r] = __shfl(invl, quad*4 + r);
#pragma unroll
  for (int nt = 0; nt < 4; ++nt)
#pragma unroll
    for (int r = 0; r < 4; ++r) {
      int qrow = qt*64 + w*16 + quad*4 + r;
      CTX[(size_t)(b*SEQ + qrow)*DIMN + hd*64 + nt*16 + ln] = o_acc[nt][r] * i4[r];
    }
}

// ===========================================================================
// Fallback fp32 path (round-1 kernels) for small ws_size.
// ===========================================================================
__global__ __launch_bounds__(256) void gemm_bt(
    const float* __restrict__ X, const float* __restrict__ W,
    const float* __restrict__ bias, float* __restrict__ C,
    int M, int N, int K)
{
  __shared__ __align__(16) float Xs[16][68];
  __shared__ __align__(16) float Ws[16][68];
  const int t  = threadIdx.x;
  const int tx = t & 15, ty = t >> 4;
  const int m0 = blockIdx.y << 6, n0 = blockIdx.x << 6;
  const int ldr = t >> 2;
  const int lk  = (t & 3) << 2;
  float acc[4][4] = {{0.f}};
  const float* Xp = X + (size_t)(m0 + ldr) * K + lk;
  const float* Wp = W + (size_t)(n0 + ldr) * K + lk;
  for (int k0 = 0; k0 < K; k0 += 16) {
    float4 xa = *(const float4*)(Xp + k0);
    float4 wa = *(const float4*)(Wp + k0);
    Xs[lk+0][ldr]=xa.x; Xs[lk+1][ldr]=xa.y; Xs[lk+2][ldr]=xa.z; Xs[lk+3][ldr]=xa.w;
    Ws[lk+0][ldr]=wa.x; Ws[lk+1][ldr]=wa.y; Ws[lk+2][ldr]=wa.z; Ws[lk+3][ldr]=wa.w;
    __syncthreads();
#pragma unroll
    for (int kk = 0; kk < 16; ++kk) {
      float4 a4 = *(const float4*)&Xs[kk][ty<<2];
      float4 b4 = *(const float4*)&Ws[kk][tx<<2];
      float av[4] = {a4.x, a4.y, a4.z, a4.w};
      float bv[4] = {b4.x, b4.y, b4.z, b4.w};
#pragma unroll
      for (int i = 0; i < 4; ++i)
#pragma unroll
        for (int j = 0; j < 4; ++j)
          acc[i][j] = fmaf(av[i], bv[j], acc[i][j]);
    }
    __syncthreads();
  }
  float4 bb4 = *(const float4*)&bias[n0 + (tx<<2)];
  const float bv[4] = {bb4.x, bb4.y, bb4.z, bb4.w};
#pragma unroll
  for (int i = 0; i < 4; ++i) {
    float4 o;
    o.x = acc[i][0]+bv[0]; o.y = acc[i][1]+bv[1];
    o.z = acc[i][2]+bv[2]; o.w = acc[i][3]+bv[3];
    *(float4*)&C[(size_t)(m0 + (ty<<2) + i) * N + n0 + (tx<<2)] = o;
  }
}

__global__ __launch_bounds__(256) void attn_fwd(
    const float* __restrict__ Q, const float* __restrict__ Kbuf,
    const float* __restrict__ Vbuf, const int* __restrict__ mask,
    float* __restrict__ CTX)
{
  __shared__ __align__(16) float Qs[64][68];
  __shared__ __align__(16) float KPs[64][68];
  __shared__ __align__(16) float Vs[64][68];
  const int t  = threadIdx.x;
  const int tx = t & 15, ty = t >> 4;
  const int qt = blockIdx.x;
  const int bh = blockIdx.y;
  const int b  = bh >> 4, h = bh & 15;
  const int ldr = t >> 2;
  const int lcb = (t & 3) << 2;
  const float* Qp = Q + (size_t)(b*SEQ + (qt<<6)) * DIMN + h*DHEAD;
#pragma unroll
  for (int u = 0; u < 4; ++u) {
    int kb = lcb + (u<<4);
    float4 q4 = *(const float4*)(Qp + (size_t)ldr*DIMN + kb);
    Qs[kb+0][ldr]=q4.x; Qs[kb+1][ldr]=q4.y; Qs[kb+2][ldr]=q4.z; Qs[kb+3][ldr]=q4.w;
  }
  float mrow[4], lsum[4], o[4][4];
#pragma unroll
  for (int i = 0; i < 4; ++i) {
    mrow[i] = -1e30f; lsum[i] = 0.f;
#pragma unroll
    for (int j = 0; j < 4; ++j) o[i][j] = 0.f;
  }
  const int qrow0 = ty << 2;
  const int col0  = tx << 2;
  for (int kt = 0; kt < SEQ/64; ++kt) {
    __syncthreads();
    const float* Kp = Kbuf + (size_t)(b*SEQ + (kt<<6)) * DIMN + h*DHEAD;
    const float* Vp = Vbuf + (size_t)(b*SEQ + (kt<<6)) * DIMN + h*DHEAD;
#pragma unroll
    for (int u = 0; u < 4; ++u) {
      int kb = lcb + (u<<4);
      float4 k4 = *(const float4*)(Kp + (size_t)ldr*DIMN + kb);
      KPs[kb+0][ldr]=k4.x; KPs[kb+1][ldr]=k4.y; KPs[kb+2][ldr]=k4.z; KPs[kb+3][ldr]=k4.w;
      float4 v4 = *(const float4*)(Vp + (size_t)ldr*DIMN + kb);
      *(float4*)&Vs[ldr][kb] = v4;
    }
    __syncthreads();
    float s[4][4] = {{0.f}};
#pragma unroll 8
    for (int kk = 0; kk < 64; ++kk) {
      float4 a4 = *(const float4*)&Qs[kk][qrow0];
      float4 b4 = *(const float4*)&KPs[kk][col0];
      float av[4] = {a4.x, a4.y, a4.z, a4.w};
      float bv[4] = {b4.x, b4.y, b4.z, b4.w};
#pragma unroll
      for (int i = 0; i < 4; ++i)
#pragma unroll
        for (int j = 0; j < 4; ++j)
          s[i][j] = fmaf(av[i], bv[j], s[i][j]);
    }
    int mk[4];
#pragma unroll
    for (int j = 0; j < 4; ++j) mk[j] = mask[b*SEQ + (kt<<6) + col0 + j];
    float p[4][4];
#pragma unroll
    for (int i = 0; i < 4; ++i) {
#pragma unroll
      for (int j = 0; j < 4; ++j)
        s[i][j] = mk[j] ? s[i][j]*0.125f : -1e30f;
      float tm = fmaxf(fmaxf(s[i][0], s[i][1]), fmaxf(s[i][2], s[i][3]));
#pragma unroll
      for (int off = 8; off >= 1; off >>= 1)
        tm = fmaxf(tm, __shfl_xor(tm, off, 64));
      float mnew  = fmaxf(mrow[i], tm);
      float alpha = __expf(mrow[i] - mnew);
      mrow[i] = mnew;
      float rsum = 0.f;
#pragma unroll
      for (int j = 0; j < 4; ++j) {
        float pv = __expf(s[i][j] - mnew);
        p[i][j] = pv; rsum += pv;
      }
#pragma unroll
      for (int off = 8; off >= 1; off >>= 1)
        rsum += __shfl_xor(rsum, off, 64);
      lsum[i] = lsum[i]*alpha + rsum;
#pragma unroll
      for (int j = 0; j < 4; ++j) o[i][j] *= alpha;
    }
    __syncthreads();
#pragma unroll
    for (int i = 0; i < 4; ++i)
#pragma unroll
      for (int j = 0; j < 4; ++j)
        KPs[col0 + j][qrow0 + i] = p[i][j];
    __syncthreads();
#pragma unroll 8
    for (int kk = 0; kk < 64; ++kk) {
      float4 a4 = *(const float4*)&KPs[kk][qrow0];
      float4 v4 = *(const float4*)&Vs[kk][col0];
      float av[4] = {a4.x, a4.y, a4.z, a4.w};
      float vv[4] = {v4.x, v4.y, v4.z, v4.w};
#pragma unroll
      for (int i = 0; i < 4; ++i)
#pragma unroll
        for (int j = 0; j < 4; ++j)
          o[i][j] = fmaf(av[i], vv[j], o[i][j]);
    }
  }
  float* Cp = CTX + (size_t)(b*SEQ + (qt<<6)) * DIMN + h*DHEAD;
#pragma unroll
  for (int i = 0; i < 4; ++i) {
    float inv = lsum[i] > 0.f ? 1.0f/lsum[i] : 0.f;
    float4 ov;
    ov.x = o[i][0]*inv; ov.y = o[i][1]*inv;
    ov.z = o[i][2]*inv; ov.w = o[i][3]*inv;
    *(float4*)(Cp + (size_t)(qrow0 + i)*DIMN + col0) = ov;
  }
}

// ---------------------------------------------------------------------------
extern "C" void kernel_launch(void* const* d_in, const int* in_sizes, int n_in,
                              void* d_out, int out_size, void* d_ws, size_t ws_size,
                              hipStream_t stream)
{
  const float* query = (const float*)d_in[0];
  const float* key   = (const float*)d_in[1];
  const float* value = (const float*)d_in[2];
  const int*   mask  = (const int*)d_in[3];
  const float* Wq = (const float*)d_in[4];
  const float* bq = (const float*)d_in[5];
  const float* Wk = (const float*)d_in[6];
  const float* bk = (const float*)d_in[7];
  const float* Wv = (const float*)d_in[8];
  const float* bv = (const float*)d_in[9];
  const float* Wo = (const float*)d_in[10];
  const float* bo = (const float*)d_in[11];
  float* out = (float*)d_out;

  const size_t E  = (size_t)MROWS * DIMN;   // 8,388,608
  const size_t WE = (size_t)DIMN * DIMN;    // 1,048,576

  // ws layout (bytes): W-packs 16 MB | XB 32 | QP 32 | KP 32 | VT 16 | F32 32 | MB
  const size_t o_XB  = 8*WE*2;              // 16,777,216
  const size_t o_QP  = o_XB  + 2*E*2;       // 50,331,648
  const size_t o_KP  = o_QP  + 2*E*2;       // 83,886,080
  const size_t o_VT  = o_KP  + 2*E*2;       // 117,440,512
  const size_t o_F32 = o_VT  + E*2;         // 134,217,728
  const size_t o_MB  = o_F32 + E*4;         // 167,772,160
  const size_t NEED  = o_MB + MROWS*4;      // 167,804,928

  if (ws_size < NEED) {
    // fallback: pure fp32 path (needs 128 MB)
    const size_t n = E;
    float* Qb = (float*)d_ws;
    float* Kb = Qb + n;
    float* Vb = Kb + n;
    float* Cb = Vb + n;
    dim3 gg(DIMN/64, MROWS/64), blk(256);
    hipLaunchKernelGGL(gemm_bt, gg, blk, 0, stream, query, Wq, bq, Qb, MROWS, DIMN, DIMN);
    hipLaunchKernelGGL(gemm_bt, gg, blk, 0, stream, key,   Wk, bk, Kb, MROWS, DIMN, DIMN);
    hipLaunchKernelGGL(gemm_bt, gg, blk, 0, stream, value, Wv, bv, Vb, MROWS, DIMN, DIMN);
    dim3 ga(SEQ/64, BSZ*NHEAD);
    hipLaunchKernelGGL(attn_fwd, ga, blk, 0, stream, Qb, Kb, Vb, mask, Cb);
    hipLaunchKernelGGL(gemm_bt, gg, blk, 0, stream, Cb, Wo, bo, out, MROWS, DIMN, DIMN);
    return;
  }

  char* W = (char*)d_ws;
  short* WQh = (short*)W;           short* WQl = WQh + WE;
  short* WKh = WQh + 2*WE;          short* WKl = WQh + 3*WE;
  short* WVh = WQh + 4*WE;          short* WVl = WQh + 5*WE;
  short* WOh = WQh + 6*WE;          short* WOl = WQh + 7*WE;
  short* XBh = (short*)(W + o_XB);  short* XBl = XBh + E;
  short* QPh = (short*)(W + o_QP);  short* QPl = QPh + E;
  short* KPh = (short*)(W + o_KP);  short* KPl = KPh + E;
  short* VTh = (short*)(W + o_VT);
  float* F32 = (float*)(W + o_F32);
  float* MB  = (float*)(W + o_MB);

  dim3 blk(256);
  dim3 gW(WE/1024), gE(E/1024);
  dim3 gg(DIMN/128, MROWS/128);       // (8, 64)
  dim3 gvt(SEQ/64, BSZ*NHEAD);        // (32, 64)
  dim3 gat(BSZ*NHEAD*SEQ/64);         // 2048

  // weight packs (q scaled by 1/sqrt(DH)=0.125, folded) + mask bias
  hipLaunchKernelGGL(pack_split, gW, blk, 0, stream, Wq, WQh, WQl, (long)WE, 0.125f);
  hipLaunchKernelGGL(pack_split, gW, blk, 0, stream, Wk, WKh, WKl, (long)WE, 1.f);
  hipLaunchKernelGGL(pack_split, gW, blk, 0, stream, Wv, WVh, WVl, (long)WE, 1.f);
  hipLaunchKernelGGL(pack_split, gW, blk, 0, stream, Wo, WOh, WOl, (long)WE, 1.f);
  hipLaunchKernelGGL(maskbias_k, dim3(MROWS/256), blk, 0, stream, mask, MB, MROWS);

  // V path
  hipLaunchKernelGGL(pack_split, gE, blk, 0, stream, value, XBh, XBl, (long)E, 1.f);
  hipLaunchKernelGGL(gemm_sp, gg, blk, 0, stream, XBh, XBl, WVh, WVl, bv, 1.f, F32, MROWS, DIMN, DIMN);
  hipLaunchKernelGGL(pack_vt, gvt, blk, 0, stream, F32, VTh);
  // Q path (bias also scaled by 0.125 per reference: q=(xWq^T+bq)/8)
  hipLaunchKernelGGL(pack_split, gE, blk, 0, stream, query, XBh, XBl, (long)E, 1.f);
  hipLaunchKernelGGL(gemm_sp, gg, blk, 0, stream, XBh, XBl, WQh, WQl, bq, 0.125f, F32, MROWS, DIMN, DIMN);
  hipLaunchKernelGGL(pack_split, gE, blk, 0, stream, F32, QPh, QPl, (long)E, 1.f);
  // K path
  hipLaunchKernelGGL(pack_split, gE, blk, 0, stream, key, XBh, XBl, (long)E, 1.f);
  hipLaunchKernelGGL(gemm_sp, gg, blk, 0, stream, XBh, XBl, WKh, WKl, bk, 1.f, F32, MROWS, DIMN, DIMN);
  hipLaunchKernelGGL(pack_split, gE, blk, 0, stream, F32, KPh, KPl, (long)E, 1.f);
  // attention (writes F32 = CTX; K-f32 content dead)
  hipLaunchKernelGGL(attn_sp, gat, blk, 0, stream, QPh, QPl, KPh, VTh, MB, F32);
  // output projection (CTX pack reuses XB; XB dead)
  hipLaunchKernelGGL(pack_split, gE, blk, 0, stream, F32, XBh, XBl, (long)E, 1.f);
  hipLaunchKernelGGL(gemm_sp, gg, blk, 0, stream, XBh, XBl, WOh, WOl, bo, 1.f, out, MROWS, DIMN, DIMN);
}

// Round 3
// 512.714 us; speedup vs baseline: 4.0133x; 1.3287x over previous
//
#include <hip/hip_runtime.h>
#include <hip/hip_bf16.h>
#include <math.h>

#define BSZ 4
#define SEQ 2048
#define DIMN 1024
#define NHEAD 16
#define DHEAD 64
#define MROWS (BSZ*SEQ)   // 8192

typedef __bf16 bf16x8 __attribute__((ext_vector_type(8)));
typedef float  f32x4  __attribute__((ext_vector_type(4)));
typedef float  fvec4  __attribute__((ext_vector_type(4)));
typedef short  s16x4  __attribute__((ext_vector_type(4)));
typedef short  s16x8  __attribute__((ext_vector_type(8)));

__device__ __forceinline__ short f2bf(float v) {
  __hip_bfloat16 b = __float2bfloat16(v);   // RNE
  return *reinterpret_cast<short*>(&b);
}
__device__ __forceinline__ float bf2f(short s) {
  __hip_bfloat16 b = *reinterpret_cast<__hip_bfloat16*>(&s);
  return __bfloat162float(b);
}

__device__ __forceinline__ void gld_lds16(const void* g, void* l) {
  __builtin_amdgcn_global_load_lds((const __attribute__((address_space(1))) void*)g,
                                   (__attribute__((address_space(3))) void*)l, 16, 0, 0);
}

// 0.125 (1/sqrt(DH)) * log2(e): folds softmax base-2 conversion into Wq/bq.
#define QSC 0.18033688011112042f

// ---------------------------------------------------------------------------
// pack_hi: fp32 -> bf16 hi plane only, with scale. n % 1024 == 0.
// ---------------------------------------------------------------------------
__global__ __launch_bounds__(256) void pack_hi(
    const float* __restrict__ x, short* __restrict__ hi, long n, float scale)
{
  long i = ((long)blockIdx.x * 256 + threadIdx.x) * 4;
  if (i >= n) return;
  fvec4 v = *(const fvec4*)&x[i];
  s16x4 h;
#pragma unroll
  for (int j = 0; j < 4; ++j) h[j] = f2bf(v[j] * scale);
  *(s16x4*)&hi[i] = h;
}

// pack_split2: fp32 -> (hi, lo) bf16 planes (used for Wo only).
__global__ __launch_bounds__(256) void pack_split2(
    const float* __restrict__ x, short* __restrict__ hi, short* __restrict__ lo,
    long n)
{
  long i = ((long)blockIdx.x * 256 + threadIdx.x) * 4;
  if (i >= n) return;
  fvec4 v = *(const fvec4*)&x[i];
  s16x4 h, l;
#pragma unroll
  for (int j = 0; j < 4; ++j) {
    short hb = f2bf(v[j]);
    h[j] = hb;
    l[j] = f2bf(v[j] - bf2f(hb));
  }
  *(s16x4*)&hi[i] = h;
  *(s16x4*)&lo[i] = l;
}

__global__ __launch_bounds__(256) void maskbias_k(
    const int* __restrict__ mask, float* __restrict__ mb, int n)
{
  int i = blockIdx.x * 256 + threadIdx.x;
  if (i < n) mb[i] = mask[i] ? 0.f : -1e30f;
}

// ---------------------------------------------------------------------------
// Single-plane bf16 MFMA GEMM (m97 structure): C = A[M,K] @ B[N,K]^T + bias*bscale
// 128x128, BK=32, 256 thr (4 waves 2x2), 16 MFMA : 8 ds_read_b128 per k-step.
// mode 0: write f32 to Cf.  mode 1: write bf16 (RNE) to Cb.
// ---------------------------------------------------------------------------
__global__ __launch_bounds__(256) void gemm_h(
    const short* __restrict__ A, const short* __restrict__ B,
    const float* __restrict__ bias, float bscale,
    float* __restrict__ Cf, short* __restrict__ Cb,
    int M, int N, int K, int mode)
{
  __shared__ __align__(16) short sA[128*32];   // 8 KB
  __shared__ __align__(16) short sB[128*32];
  const int t = threadIdx.x;
  const int ln = t & 15, quad = (t & 63) >> 4, w = t >> 6;
  const int wm = w >> 1, wn = w & 1;
  const int m0 = blockIdx.y * 128, n0 = blockIdx.x * 128;
  const int lrow = t >> 2, lko = (t & 3) * 8;
  f32x4 acc[4][4];
#pragma unroll
  for (int i = 0; i < 4; ++i)
#pragma unroll
    for (int j = 0; j < 4; ++j) acc[i][j] = (f32x4){0.f,0.f,0.f,0.f};

  for (int k0 = 0; k0 < K; k0 += 32) {
    __syncthreads();
#pragma unroll
    for (int u = 0; u < 2; ++u) {
      int row = u*64 + lrow;
      gld_lds16(A + (size_t)(m0+row)*K + k0 + lko, sA + u*2048 + t*8);
      gld_lds16(B + (size_t)(n0+row)*K + k0 + lko, sB + u*2048 + t*8);
    }
    __syncthreads();
    bf16x8 af[4], bfr[4];
#pragma unroll
    for (int mt = 0; mt < 4; ++mt)
      af[mt] = *(bf16x8*)&sA[(wm*64 + mt*16 + ln)*32 + quad*8];
#pragma unroll
    for (int nt = 0; nt < 4; ++nt)
      bfr[nt] = *(bf16x8*)&sB[(wn*64 + nt*16 + ln)*32 + quad*8];
#pragma unroll
    for (int mt = 0; mt < 4; ++mt)
#pragma unroll
      for (int nt = 0; nt < 4; ++nt)
        acc[mt][nt] = __builtin_amdgcn_mfma_f32_16x16x32_bf16(af[mt], bfr[nt], acc[mt][nt], 0, 0, 0);
  }
#pragma unroll
  for (int nt = 0; nt < 4; ++nt) {
    int col = n0 + wn*64 + nt*16 + ln;
    float bv = bias[col] * bscale;
#pragma unroll
    for (int mt = 0; mt < 4; ++mt)
#pragma unroll
      for (int r = 0; r < 4; ++r) {
        int row = m0 + wm*64 + mt*16 + quad*4 + r;
        float val = acc[mt][nt][r] + bv;
        if (mode == 0) Cf[(size_t)row*N + col] = val;
        else           Cb[(size_t)row*N + col] = f2bf(val);
      }
  }
}

// ---------------------------------------------------------------------------
// 3-term split-bf16 GEMM (O-projection): C = (Ah+Al) @ (Bh+Bl)^T + bias
// ---------------------------------------------------------------------------
__global__ __launch_bounds__(256) void gemm_sp(
    const short* __restrict__ Ah, const short* __restrict__ Al,
    const short* __restrict__ Bh, const short* __restrict__ Bl,
    const float* __restrict__ bias, float bscale,
    float* __restrict__ C, int M, int N, int K)
{
  __shared__ __align__(16) short sA[2*128*32];   // 16 KB
  __shared__ __align__(16) short sB[2*128*32];
  const int t = threadIdx.x;
  const int ln = t & 15, quad = (t & 63) >> 4, w = t >> 6;
  const int wm = w >> 1, wn = w & 1;
  const int m0 = blockIdx.y * 128, n0 = blockIdx.x * 128;
  const int lrow = t >> 2, lko = (t & 3) * 8;
  f32x4 acc[4][4];
#pragma unroll
  for (int i = 0; i < 4; ++i)
#pragma unroll
    for (int j = 0; j < 4; ++j) acc[i][j] = (f32x4){0.f,0.f,0.f,0.f};

  for (int k0 = 0; k0 < K; k0 += 32) {
    __syncthreads();
#pragma unroll
    for (int u = 0; u < 2; ++u) {
      int row = u*64 + lrow;
      gld_lds16(Ah + (size_t)(m0+row)*K + k0 + lko, sA + u*2048 + t*8);
      gld_lds16(Al + (size_t)(m0+row)*K + k0 + lko, sA + 4096 + u*2048 + t*8);
      gld_lds16(Bh + (size_t)(n0+row)*K + k0 + lko, sB + u*2048 + t*8);
      gld_lds16(Bl + (size_t)(n0+row)*K + k0 + lko, sB + 4096 + u*2048 + t*8);
    }
    __syncthreads();
    bf16x8 ah[4], al[4], bh[4], bl[4];
#pragma unroll
    for (int mt = 0; mt < 4; ++mt) {
      int r = wm*64 + mt*16 + ln;
      ah[mt] = *(bf16x8*)&sA[r*32 + quad*8];
      al[mt] = *(bf16x8*)&sA[4096 + r*32 + quad*8];
    }
#pragma unroll
    for (int nt = 0; nt < 4; ++nt) {
      int r = wn*64 + nt*16 + ln;
      bh[nt] = *(bf16x8*)&sB[r*32 + quad*8];
      bl[nt] = *(bf16x8*)&sB[4096 + r*32 + quad*8];
    }
#pragma unroll
    for (int mt = 0; mt < 4; ++mt)
#pragma unroll
      for (int nt = 0; nt < 4; ++nt) {
        acc[mt][nt] = __builtin_amdgcn_mfma_f32_16x16x32_bf16(ah[mt], bh[nt], acc[mt][nt], 0, 0, 0);
        acc[mt][nt] = __builtin_amdgcn_mfma_f32_16x16x32_bf16(ah[mt], bl[nt], acc[mt][nt], 0, 0, 0);
        acc[mt][nt] = __builtin_amdgcn_mfma_f32_16x16x32_bf16(al[mt], bh[nt], acc[mt][nt], 0, 0, 0);
      }
  }
#pragma unroll
  for (int nt = 0; nt < 4; ++nt) {
    float bv = bias[n0 + wn*64 + nt*16 + ln] * bscale;
#pragma unroll
    for (int mt = 0; mt < 4; ++mt)
#pragma unroll
      for (int r = 0; r < 4; ++r)
        C[(size_t)(m0 + wm*64 + mt*16 + quad*4 + r)*N + (n0 + wn*64 + nt*16 + ln)] =
            acc[mt][nt][r] + bv;
  }
}

// ---------------------------------------------------------------------------
// pack_vt_b: V bf16 [b][s][1024] -> Vt bf16 [bh][d(64)][s(2048)]
// ---------------------------------------------------------------------------
__global__ __launch_bounds__(256) void pack_vt_b(
    const short* __restrict__ VB, short* __restrict__ VT)
{
  __shared__ short sh[64][72];
  const int t = threadIdx.x;
  const int st = blockIdx.x, bh = blockIdx.y;
  const int b = bh >> 4, hd = bh & 15;
  const int s0 = st * 64;
#pragma unroll
  for (int u = 0; u < 4; ++u) {
    int c = u*256 + t;
    int s = c >> 4, d4 = (c & 15) * 4;
    s16x4 v = *(const s16x4*)&VB[(size_t)(b*SEQ + s0 + s)*DIMN + hd*64 + d4];
    sh[s][d4] = v[0]; sh[s][d4+1] = v[1]; sh[s][d4+2] = v[2]; sh[s][d4+3] = v[3];
  }
  __syncthreads();
#pragma unroll
  for (int u = 0; u < 2; ++u) {
    int c = u*256 + t;
    int d = c >> 3, s8 = (c & 7) * 8;
    s16x8 h;
#pragma unroll
    for (int j = 0; j < 8; ++j) h[j] = sh[s8+j][d];
    *(s16x8*)&VT[((size_t)bh*64 + d)*SEQ + s0 + s8] = h;
  }
}

// ---------------------------------------------------------------------------
// Flash attention, single-plane bf16. Block = (b,h) x 64-row Q tile; 4 waves.
// Scores transposed St[kc][q] = K·Q^T; per-lane softmax state (q = lane&15).
// Logits already in base-2 domain (QSC folded into Wq/bq) -> exp2f.
// P single bf16 via LDS (stride 72). Epilogue writes ctx hi+lo bf16 planes.
// ---------------------------------------------------------------------------
__global__ __launch_bounds__(256) void attn_sp2(
    const short* __restrict__ QB, const short* __restrict__ KB,
    const short* __restrict__ VT, const float* __restrict__ mb,
    short* __restrict__ CTXh, short* __restrict__ CTXl)
{
  __shared__ __align__(16) short sQ[2*64*32];   // 8 KB
  __shared__ __align__(16) short sK[2*64*32];   // 8 KB
  __shared__ __align__(16) short sV[2*64*32];   // 8 KB
  __shared__ __align__(16) short sP[64*72];     // 9 KB
  const int t = threadIdx.x;
  const int ln = t & 15, quad = (t & 63) >> 4, w = t >> 6;
  const int g = blockIdx.x;
  const int chunk = g >> 3, qt = chunk & 31, bh = ((chunk >> 5) << 3) + (g & 7);
  const int b = bh >> 4, hd = bh & 15;
  const int lrow = t >> 2, lko = (t & 3) * 8;

  // stage Q (once)
#pragma unroll
  for (int h = 0; h < 2; ++h)
    gld_lds16(QB + (size_t)(b*SEQ + qt*64 + lrow)*DIMN + hd*64 + h*32 + lko,
              sQ + h*2048 + t*8);
  __syncthreads();
  bf16x8 qf[2];
#pragma unroll
  for (int ks = 0; ks < 2; ++ks)
    qf[ks] = *(bf16x8*)&sQ[ks*2048 + (w*16+ln)*32 + quad*8];

  f32x4 o_acc[4];
#pragma unroll
  for (int nt = 0; nt < 4; ++nt) o_acc[nt] = (f32x4){0.f,0.f,0.f,0.f};
  float m_run = -1e30f, l_run = 0.f;

  for (int kt = 0; kt < SEQ/64; ++kt) {
    __syncthreads();
#pragma unroll
    for (int h = 0; h < 2; ++h) {
      gld_lds16(KB + (size_t)(b*SEQ + kt*64 + lrow)*DIMN + hd*64 + h*32 + lko,
                sK + h*2048 + t*8);
      gld_lds16(VT + ((size_t)bh*64 + lrow)*SEQ + kt*64 + h*32 + lko,
                sV + h*2048 + t*8);
    }
    __syncthreads();

    // St[kc][q] = K·Q^T
    f32x4 sacc[4];
#pragma unroll
    for (int mt = 0; mt < 4; ++mt) sacc[mt] = (f32x4){0.f,0.f,0.f,0.f};
#pragma unroll
    for (int ks = 0; ks < 2; ++ks)
#pragma unroll
      for (int mt = 0; mt < 4; ++mt) {
        bf16x8 kf = *(bf16x8*)&sK[ks*2048 + (mt*16+ln)*32 + quad*8];
        sacc[mt] = __builtin_amdgcn_mfma_f32_16x16x32_bf16(kf, qf[ks], sacc[mt], 0, 0, 0);
      }

    // mask bias + online softmax (base-2 domain)
    float sv[4][4];
    float tmax = -1e30f;
#pragma unroll
    for (int mt = 0; mt < 4; ++mt) {
      fvec4 mbv = *(const fvec4*)&mb[b*SEQ + kt*64 + mt*16 + quad*4];
#pragma unroll
      for (int r = 0; r < 4; ++r) {
        sv[mt][r] = sacc[mt][r] + mbv[r];
        tmax = fmaxf(tmax, sv[mt][r]);
      }
    }
    tmax = fmaxf(tmax, __shfl_xor(tmax, 16));
    tmax = fmaxf(tmax, __shfl_xor(tmax, 32));
    float mnew  = fmaxf(m_run, tmax);
    float alpha = exp2f(m_run - mnew);
    m_run = mnew;
    float rs = 0.f;
    const int q = w*16 + ln;
#pragma unroll
    for (int mt = 0; mt < 4; ++mt) {
      s16x4 ph;
#pragma unroll
      for (int r = 0; r < 4; ++r) {
        float p = exp2f(sv[mt][r] - mnew);
        rs += p;
        ph[r] = f2bf(p);
      }
      *(s16x4*)&sP[q*72 + mt*16 + quad*4] = ph;
    }
    rs += __shfl_xor(rs, 16);
    rs += __shfl_xor(rs, 32);
    l_run = l_run * alpha + rs;

    // rescale O (row q' = quad*4+r)
    float a4[4];
#pragma unroll
    for (int r = 0; r < 4; ++r) a4[r] = __shfl(alpha, quad*4 + r);
#pragma unroll
    for (int nt = 0; nt < 4; ++nt)
#pragma unroll
      for (int r = 0; r < 4; ++r) o_acc[nt][r] *= a4[r];

    // O += P·V   (P rows are wave-private: no barrier needed)
#pragma unroll
    for (int ks = 0; ks < 2; ++ks) {
      bf16x8 pf = *(bf16x8*)&sP[(w*16+ln)*72 + ks*32 + quad*8];
#pragma unroll
      for (int nt = 0; nt < 4; ++nt) {
        bf16x8 vf = *(bf16x8*)&sV[ks*2048 + (nt*16+ln)*32 + quad*8];
        o_acc[nt] = __builtin_amdgcn_mfma_f32_16x16x32_bf16(pf, vf, o_acc[nt], 0, 0, 0);
      }
    }
  }

  float invl = (l_run > 0.f) ? 1.f / l_run : 0.f;
  float i4[4];
#pragma unroll
  for (int r = 0; r < 4; ++r) i4[r] = __shfl(invl, quad*4 + r);
#pragma unroll
  for (int nt = 0; nt < 4; ++nt)
#pragma unroll
    for (int r = 0; r < 4; ++r) {
      int qrow = qt*64 + w*16 + quad*4 + r;
      size_t idx = (size_t)(b*SEQ + qrow)*DIMN + hd*64 + nt*16 + ln;
      float val = o_acc[nt][r] * i4[r];
      short hb = f2bf(val);
      CTXh[idx] = hb;
      CTXl[idx] = f2bf(val - bf2f(hb));
    }
}

// ===========================================================================
// Fallback fp32 path for small ws_size.
// ===========================================================================
__global__ __launch_bounds__(256) void gemm_bt(
    const float* __restrict__ X, const float* __restrict__ W,
    const float* __restrict__ bias, float* __restrict__ C,
    int M, int N, int K)
{
  __shared__ __align__(16) float Xs[16][68];
  __shared__ __align__(16) float Ws[16][68];
  const int t  = threadIdx.x;
  const int tx = t & 15, ty = t >> 4;
  const int m0 = blockIdx.y << 6, n0 = blockIdx.x << 6;
  const int ldr = t >> 2;
  const int lk  = (t & 3) << 2;
  float acc[4][4] = {{0.f}};
  const float* Xp = X + (size_t)(m0 + ldr) * K + lk;
  const float* Wp = W + (size_t)(n0 + ldr) * K + lk;
  for (int k0 = 0; k0 < K; k0 += 16) {
    float4 xa = *(const float4*)(Xp + k0);
    float4 wa = *(const float4*)(Wp + k0);
    Xs[lk+0][ldr]=xa.x; Xs[lk+1][ldr]=xa.y; Xs[lk+2][ldr]=xa.z; Xs[lk+3][ldr]=xa.w;
    Ws[lk+0][ldr]=wa.x; Ws[lk+1][ldr]=wa.y; Ws[lk+2][ldr]=wa.z; Ws[lk+3][ldr]=wa.w;
    __syncthreads();
#pragma unroll
    for (int kk = 0; kk < 16; ++kk) {
      float4 a4 = *(const float4*)&Xs[kk][ty<<2];
      float4 b4 = *(const float4*)&Ws[kk][tx<<2];
      float av[4] = {a4.x, a4.y, a4.z, a4.w};
      float bv[4] = {b4.x, b4.y, b4.z, b4.w};
#pragma unroll
      for (int i = 0; i < 4; ++i)
#pragma unroll
        for (int j = 0; j < 4; ++j)
          acc[i][j] = fmaf(av[i], bv[j], acc[i][j]);
    }
    __syncthreads();
  }
  float4 bb4 = *(const float4*)&bias[n0 + (tx<<2)];
  const float bv[4] = {bb4.x, bb4.y, bb4.z, bb4.w};
#pragma unroll
  for (int i = 0; i < 4; ++i) {
    float4 o;
    o.x = acc[i][0]+bv[0]; o.y = acc[i][1]+bv[1];
    o.z = acc[i][2]+bv[2]; o.w = acc[i][3]+bv[3];
    *(float4*)&C[(size_t)(m0 + (ty<<2) + i) * N + n0 + (tx<<2)] = o;
  }
}

__global__ __launch_bounds__(256) void attn_fwd(
    const float* __restrict__ Q, const float* __restrict__ Kbuf,
    const float* __restrict__ Vbuf, const int* __restrict__ mask,
    float* __restrict__ CTX)
{
  __shared__ __align__(16) float Qs[64][68];
  __shared__ __align__(16) float KPs[64][68];
  __shared__ __align__(16) float Vs[64][68];
  const int t  = threadIdx.x;
  const int tx = t & 15, ty = t >> 4;
  const int qt = blockIdx.x;
  const int bh = blockIdx.y;
  const int b  = bh >> 4, h = bh & 15;
  const int ldr = t >> 2;
  const int lcb = (t & 3) << 2;
  const float* Qp = Q + (size_t)(b*SEQ + (qt<<6)) * DIMN + h*DHEAD;
#pragma unroll
  for (int u = 0; u < 4; ++u) {
    int kb = lcb + (u<<4);
    float4 q4 = *(const float4*)(Qp + (size_t)ldr*DIMN + kb);
    Qs[kb+0][ldr]=q4.x; Qs[kb+1][ldr]=q4.y; Qs[kb+2][ldr]=q4.z; Qs[kb+3][ldr]=q4.w;
  }
  float mrow[4], lsum[4], o[4][4];
#pragma unroll
  for (int i = 0; i < 4; ++i) {
    mrow[i] = -1e30f; lsum[i] = 0.f;
#pragma unroll
    for (int j = 0; j < 4; ++j) o[i][j] = 0.f;
  }
  const int qrow0 = ty << 2;
  const int col0  = tx << 2;
  for (int kt = 0; kt < SEQ/64; ++kt) {
    __syncthreads();
    const float* Kp = Kbuf + (size_t)(b*SEQ + (kt<<6)) * DIMN + h*DHEAD;
    const float* Vp = Vbuf + (size_t)(b*SEQ + (kt<<6)) * DIMN + h*DHEAD;
#pragma unroll
    for (int u = 0; u < 4; ++u) {
      int kb = lcb + (u<<4);
      float4 k4 = *(const float4*)(Kp + (size_t)ldr*DIMN + kb);
      KPs[kb+0][ldr]=k4.x; KPs[kb+1][ldr]=k4.y; KPs[kb+2][ldr]=k4.z; KPs[kb+3][ldr]=k4.w;
      float4 v4 = *(const float4*)(Vp + (size_t)ldr*DIMN + kb);
      *(float4*)&Vs[ldr][kb] = v4;
    }
    __syncthreads();
    float s[4][4] = {{0.f}};
#pragma unroll 8
    for (int kk = 0; kk < 64; ++kk) {
      float4 a4 = *(const float4*)&Qs[kk][qrow0];
      float4 b4 = *(const float4*)&KPs[kk][col0];
      float av[4] = {a4.x, a4.y, a4.z, a4.w};
      float bv[4] = {b4.x, b4.y, b4.z, b4.w};
#pragma unroll
      for (int i = 0; i < 4; ++i)
#pragma unroll
        for (int j = 0; j < 4; ++j)
          s[i][j] = fmaf(av[i], bv[j], s[i][j]);
    }
    int mk[4];
#pragma unroll
    for (int j = 0; j < 4; ++j) mk[j] = mask[b*SEQ + (kt<<6) + col0 + j];
    float p[4][4];
#pragma unroll
    for (int i = 0; i < 4; ++i) {
#pragma unroll
      for (int j = 0; j < 4; ++j)
        s[i][j] = mk[j] ? s[i][j]*0.125f : -1e30f;
      float tm = fmaxf(fmaxf(s[i][0], s[i][1]), fmaxf(s[i][2], s[i][3]));
#pragma unroll
      for (int off = 8; off >= 1; off >>= 1)
        tm = fmaxf(tm, __shfl_xor(tm, off, 64));
      float mnew  = fmaxf(mrow[i], tm);
      float alpha = __expf(mrow[i] - mnew);
      mrow[i] = mnew;
      float rsum = 0.f;
#pragma unroll
      for (int j = 0; j < 4; ++j) {
        float pv = __expf(s[i][j] - mnew);
        p[i][j] = pv; rsum += pv;
      }
#pragma unroll
      for (int off = 8; off >= 1; off >>= 1)
        rsum += __shfl_xor(rsum, off, 64);
      lsum[i] = lsum[i]*alpha + rsum;
#pragma unroll
      for (int j = 0; j < 4; ++j) o[i][j] *= alpha;
    }
    __syncthreads();
#pragma unroll
    for (int i = 0; i < 4; ++i)
#pragma unroll
      for (int j = 0; j < 4; ++j)
        KPs[col0 + j][qrow0 + i] = p[i][j];
    __syncthreads();
#pragma unroll 8
    for (int kk = 0; kk < 64; ++kk) {
      float4 a4 = *(const float4*)&KPs[kk][qrow0];
      float4 v4 = *(const float4*)&Vs[kk][col0];
      float av[4] = {a4.x, a4.y, a4.z, a4.w};
      float vv[4] = {v4.x, v4.y, v4.z, v4.w};
#pragma unroll
      for (int i = 0; i < 4; ++i)
#pragma unroll
        for (int j = 0; j < 4; ++j)
          o[i][j] = fmaf(av[i], vv[j], o[i][j]);
    }
  }
  float* Cp = CTX + (size_t)(b*SEQ + (qt<<6)) * DIMN + h*DHEAD;
#pragma unroll
  for (int i = 0; i < 4; ++i) {
    float inv = lsum[i] > 0.f ? 1.0f/lsum[i] : 0.f;
    float4 ov;
    ov.x = o[i][0]*inv; ov.y = o[i][1]*inv;
    ov.z = o[i][2]*inv; ov.w = o[i][3]*inv;
    *(float4*)(Cp + (size_t)(qrow0 + i)*DIMN + col0) = ov;
  }
}

// ---------------------------------------------------------------------------
extern "C" void kernel_launch(void* const* d_in, const int* in_sizes, int n_in,
                              void* d_out, int out_size, void* d_ws, size_t ws_size,
                              hipStream_t stream)
{
  const float* query = (const float*)d_in[0];
  const float* key   = (const float*)d_in[1];
  const float* value = (const float*)d_in[2];
  const int*   mask  = (const int*)d_in[3];
  const float* Wq = (const float*)d_in[4];
  const float* bq = (const float*)d_in[5];
  const float* Wk = (const float*)d_in[6];
  const float* bk = (const float*)d_in[7];
  const float* Wv = (const float*)d_in[8];
  const float* bv = (const float*)d_in[9];
  const float* Wo = (const float*)d_in[10];
  const float* bo = (const float*)d_in[11];
  float* out = (float*)d_out;

  const size_t E  = (size_t)MROWS * DIMN;   // 8,388,608
  const size_t WE = (size_t)DIMN * DIMN;    // 1,048,576

  // ws layout (all bf16 planes are E or WE shorts)
  // [WQh WKh WVh WOh WOl][XB][QB][KB][VB][VT][CTXh][CTXl][MB]
  const size_t o_XB   = 5*WE*2;                 // 10 MB
  const size_t o_QB   = o_XB   + E*2;
  const size_t o_KB   = o_QB   + E*2;
  const size_t o_VB   = o_KB   + E*2;
  const size_t o_VT   = o_VB   + E*2;
  const size_t o_CTXh = o_VT   + E*2;
  const size_t o_CTXl = o_CTXh + E*2;
  const size_t o_MB   = o_CTXl + E*2;
  const size_t NEED   = o_MB + MROWS*4;         // ~128 MB

  if (ws_size < NEED) {
    const size_t n = E;
    float* Qb = (float*)d_ws;
    float* Kb = Qb + n;
    float* Vb = Kb + n;
    float* Cb = Vb + n;
    dim3 gg(DIMN/64, MROWS/64), blk(256);
    hipLaunchKernelGGL(gemm_bt, gg, blk, 0, stream, query, Wq, bq, Qb, MROWS, DIMN, DIMN);
    hipLaunchKernelGGL(gemm_bt, gg, blk, 0, stream, key,   Wk, bk, Kb, MROWS, DIMN, DIMN);
    hipLaunchKernelGGL(gemm_bt, gg, blk, 0, stream, value, Wv, bv, Vb, MROWS, DIMN, DIMN);
    dim3 ga(SEQ/64, BSZ*NHEAD);
    hipLaunchKernelGGL(attn_fwd, ga, blk, 0, stream, Qb, Kb, Vb, mask, Cb);
    hipLaunchKernelGGL(gemm_bt, gg, blk, 0, stream, Cb, Wo, bo, out, MROWS, DIMN, DIMN);
    return;
  }

  char* Wp = (char*)d_ws;
  short* WQh = (short*)Wp;
  short* WKh = WQh + WE;
  short* WVh = WQh + 2*WE;
  short* WOh = WQh + 3*WE;
  short* WOl = WQh + 4*WE;
  short* XB   = (short*)(Wp + o_XB);
  short* QB   = (short*)(Wp + o_QB);
  short* KB   = (short*)(Wp + o_KB);
  short* VB   = (short*)(Wp + o_VB);
  short* VT   = (short*)(Wp + o_VT);
  short* CTXh = (short*)(Wp + o_CTXh);
  short* CTXl = (short*)(Wp + o_CTXl);
  float* MB   = (float*)(Wp + o_MB);

  dim3 blk(256);
  dim3 gW(WE/1024), gE(E/1024);
  dim3 gg(DIMN/128, MROWS/128);       // (8, 64)
  dim3 gvt(SEQ/64, BSZ*NHEAD);        // (32, 64)
  dim3 gat(BSZ*NHEAD*SEQ/64);         // 2048

  // weight packs + mask bias
  hipLaunchKernelGGL(pack_hi, gW, blk, 0, stream, Wq, WQh, (long)WE, QSC);
  hipLaunchKernelGGL(pack_hi, gW, blk, 0, stream, Wk, WKh, (long)WE, 1.f);
  hipLaunchKernelGGL(pack_hi, gW, blk, 0, stream, Wv, WVh, (long)WE, 1.f);
  hipLaunchKernelGGL(pack_split2, gW, blk, 0, stream, Wo, WOh, WOl, (long)WE);
  hipLaunchKernelGGL(maskbias_k, dim3(MROWS/256), blk, 0, stream, mask, MB, MROWS);

  // projections (single-term bf16, epilogue writes bf16 directly)
  hipLaunchKernelGGL(pack_hi, gE, blk, 0, stream, query, XB, (long)E, 1.f);
  hipLaunchKernelGGL(gemm_h, gg, blk, 0, stream, XB, WQh, bq, QSC, (float*)nullptr, QB, MROWS, DIMN, DIMN, 1);
  hipLaunchKernelGGL(pack_hi, gE, blk, 0, stream, key, XB, (long)E, 1.f);
  hipLaunchKernelGGL(gemm_h, gg, blk, 0, stream, XB, WKh, bk, 1.f, (float*)nullptr, KB, MROWS, DIMN, DIMN, 1);
  hipLaunchKernelGGL(pack_hi, gE, blk, 0, stream, value, XB, (long)E, 1.f);
  hipLaunchKernelGGL(gemm_h, gg, blk, 0, stream, XB, WVh, bv, 1.f, (float*)nullptr, VB, MROWS, DIMN, DIMN, 1);
  hipLaunchKernelGGL(pack_vt_b, gvt, blk, 0, stream, VB, VT);

  // attention -> ctx hi/lo
  hipLaunchKernelGGL(attn_sp2, gat, blk, 0, stream, QB, KB, VT, MB, CTXh, CTXl);

  // output projection (3-term split)
  hipLaunchKernelGGL(gemm_sp, gg, blk, 0, stream, CTXh, CTXl, WOh, WOl, bo, 1.f, out, MROWS, DIMN, DIMN);
}

// Round 4
// 455.720 us; speedup vs baseline: 4.5152x; 1.1251x over previous
//
#include <hip/hip_runtime.h>
#include <hip/hip_bf16.h>
#include <math.h>

#define BSZ 4
#define SEQ 2048
#define DIMN 1024
#define NHEAD 16
#define DHEAD 64
#define MROWS (BSZ*SEQ)   // 8192

typedef __bf16 bf16x8 __attribute__((ext_vector_type(8)));
typedef float  f32x4  __attribute__((ext_vector_type(4)));
typedef float  fvec4  __attribute__((ext_vector_type(4)));
typedef short  s16x4  __attribute__((ext_vector_type(4)));
typedef short  s16x8  __attribute__((ext_vector_type(8)));

__device__ __forceinline__ short f2bf(float v) {
  __hip_bfloat16 b = __float2bfloat16(v);   // RNE
  return *reinterpret_cast<short*>(&b);
}
__device__ __forceinline__ float bf2f(short s) {
  __hip_bfloat16 b = *reinterpret_cast<__hip_bfloat16*>(&s);
  return __bfloat162float(b);
}

__device__ __forceinline__ void gld_lds16(const void* g, void* l) {
  __builtin_amdgcn_global_load_lds((const __attribute__((address_space(1))) void*)g,
                                   (__attribute__((address_space(3))) void*)l, 16, 0, 0);
}

// 0.125 (1/sqrt(DH)) * log2(e): folds softmax base-2 conversion into Wq/bq.
#define QSC 0.18033688011112042f

// ---------------------------------------------------------------------------
// pack_w4: all four weight packs in one launch. y=0 Wq*QSC hi, 1 Wk hi,
// 2 Wv hi, 3 Wo hi+lo.
// ---------------------------------------------------------------------------
__global__ __launch_bounds__(256) void pack_w4(
    const float* __restrict__ Wq, const float* __restrict__ Wk,
    const float* __restrict__ Wv, const float* __restrict__ Wo,
    short* __restrict__ WQh, short* __restrict__ WKh,
    short* __restrict__ WVh, short* __restrict__ WOh, short* __restrict__ WOl,
    long n)
{
  long i = ((long)blockIdx.x * 256 + threadIdx.x) * 4;
  if (i >= n) return;
  int which = blockIdx.y;
  if (which == 3) {
    fvec4 v = *(const fvec4*)&Wo[i];
    s16x4 h, l;
#pragma unroll
    for (int j = 0; j < 4; ++j) {
      short hb = f2bf(v[j]);
      h[j] = hb;
      l[j] = f2bf(v[j] - bf2f(hb));
    }
    *(s16x4*)&WOh[i] = h;
    *(s16x4*)&WOl[i] = l;
  } else {
    const float* src = which == 0 ? Wq : (which == 1 ? Wk : Wv);
    short* dst = which == 0 ? WQh : (which == 1 ? WKh : WVh);
    float sc = which == 0 ? QSC : 1.f;
    fvec4 v = *(const fvec4*)&src[i];
    s16x4 h;
#pragma unroll
    for (int j = 0; j < 4; ++j) h[j] = f2bf(v[j] * sc);
    *(s16x4*)&dst[i] = h;
  }
}

// pack_hi3: query/key/value -> bf16 hi planes, one launch (y selects).
__global__ __launch_bounds__(256) void pack_hi3(
    const float* __restrict__ q, const float* __restrict__ k,
    const float* __restrict__ v,
    short* __restrict__ xq, short* __restrict__ xk, short* __restrict__ xv,
    long n)
{
  long i = ((long)blockIdx.x * 256 + threadIdx.x) * 4;
  if (i >= n) return;
  const float* src = blockIdx.y == 0 ? q : (blockIdx.y == 1 ? k : v);
  short* dst = blockIdx.y == 0 ? xq : (blockIdx.y == 1 ? xk : xv);
  fvec4 x = *(const fvec4*)&src[i];
  s16x4 h;
#pragma unroll
  for (int j = 0; j < 4; ++j) h[j] = f2bf(x[j]);
  *(s16x4*)&dst[i] = h;
}

__global__ __launch_bounds__(256) void maskbias_k(
    const int* __restrict__ mask, float* __restrict__ mb, int n)
{
  int i = blockIdx.x * 256 + threadIdx.x;
  if (i < n) mb[i] = mask[i] ? 0.f : -1e30f;
}

// per-(b, 128-key-chunk) all-valid flags (64 chunks)
__global__ __launch_bounds__(64) void mask_flags(
    const int* __restrict__ mask, int* __restrict__ flg)
{
  int c = blockIdx.x;               // 0..63: b = c>>4, chunk = c&15
  int base = (c >> 4) * SEQ + (c & 15) * 128;
  int m0 = mask[base + threadIdx.x];
  int m1 = mask[base + 64 + threadIdx.x];
  unsigned long long bal = __ballot(m0 != 0 && m1 != 0);
  if (threadIdx.x == 0) flg[c] = (bal == ~0ull) ? 1 : 0;
}

// ---------------------------------------------------------------------------
// Single-plane bf16 MFMA GEMM, XOR-swizzled LDS. C = A[M,K] @ B[N,K]^T + bias
// mode 0: f32 -> Cf. mode 1: bf16 -> Cb ([M,N]). mode 2: bf16 -> Cb in
// VT layout [(b*16+hd)*64+dd][SEQ] (fused V transpose).
// ---------------------------------------------------------------------------
__global__ __launch_bounds__(256) void gemm_h(
    const short* __restrict__ A, const short* __restrict__ B,
    const float* __restrict__ bias, float bscale,
    float* __restrict__ Cf, short* __restrict__ Cb,
    int M, int N, int K, int mode)
{
  __shared__ __align__(16) short sA[128*32];   // 8 KB
  __shared__ __align__(16) short sB[128*32];
  const int t = threadIdx.x;
  const int ln = t & 15, quad = (t & 63) >> 4, w = t >> 6;
  const int wm = w >> 1, wn = w & 1;
  const int m0 = blockIdx.y * 128, n0 = blockIdx.x * 128;
  const int lrow = t >> 2;
  const int lko = (((t & 3) ^ ((t >> 3) & 3))) * 8;   // XOR-swizzled k-chunk
  const int fsw = ((ln >> 1) & 3);                     // frag-read swizzle key
  f32x4 acc[4][4];
#pragma unroll
  for (int i = 0; i < 4; ++i)
#pragma unroll
    for (int j = 0; j < 4; ++j) acc[i][j] = (f32x4){0.f,0.f,0.f,0.f};

  for (int k0 = 0; k0 < K; k0 += 32) {
    __syncthreads();
#pragma unroll
    for (int u = 0; u < 2; ++u) {
      int row = u*64 + lrow;
      gld_lds16(A + (size_t)(m0+row)*K + k0 + lko, sA + u*2048 + t*8);
      gld_lds16(B + (size_t)(n0+row)*K + k0 + lko, sB + u*2048 + t*8);
    }
    __syncthreads();
    bf16x8 af[4], bfr[4];
#pragma unroll
    for (int mt = 0; mt < 4; ++mt)
      af[mt] = *(bf16x8*)&sA[(wm*64 + mt*16 + ln)*32 + (quad ^ fsw)*8];
#pragma unroll
    for (int nt = 0; nt < 4; ++nt)
      bfr[nt] = *(bf16x8*)&sB[(wn*64 + nt*16 + ln)*32 + (quad ^ fsw)*8];
#pragma unroll
    for (int mt = 0; mt < 4; ++mt)
#pragma unroll
      for (int nt = 0; nt < 4; ++nt)
        acc[mt][nt] = __builtin_amdgcn_mfma_f32_16x16x32_bf16(af[mt], bfr[nt], acc[mt][nt], 0, 0, 0);
  }
#pragma unroll
  for (int nt = 0; nt < 4; ++nt) {
    int col = n0 + wn*64 + nt*16 + ln;
    float bv = bias[col] * bscale;
    if (mode == 2) {
      int hd = col >> 6, dd = col & 63;
#pragma unroll
      for (int mt = 0; mt < 4; ++mt) {
        int sg = m0 + wm*64 + mt*16 + quad*4;
        int b = sg >> 11, s = sg & 2047;
        s16x4 h;
#pragma unroll
        for (int r = 0; r < 4; ++r) h[r] = f2bf(acc[mt][nt][r] + bv);
        *(s16x4*)&Cb[((size_t)((b*16 + hd)*64 + dd))*SEQ + s] = h;
      }
    } else {
#pragma unroll
      for (int mt = 0; mt < 4; ++mt)
#pragma unroll
        for (int r = 0; r < 4; ++r) {
          int row = m0 + wm*64 + mt*16 + quad*4 + r;
          float val = acc[mt][nt][r] + bv;
          if (mode == 0) Cf[(size_t)row*N + col] = val;
          else           Cb[(size_t)row*N + col] = f2bf(val);
        }
    }
  }
}

// ---------------------------------------------------------------------------
// 3-term split-bf16 GEMM (O-projection), XOR-swizzled LDS.
// ---------------------------------------------------------------------------
__global__ __launch_bounds__(256) void gemm_sp(
    const short* __restrict__ Ah, const short* __restrict__ Al,
    const short* __restrict__ Bh, const short* __restrict__ Bl,
    const float* __restrict__ bias, float bscale,
    float* __restrict__ C, int M, int N, int K)
{
  __shared__ __align__(16) short sA[2*128*32];   // 16 KB
  __shared__ __align__(16) short sB[2*128*32];
  const int t = threadIdx.x;
  const int ln = t & 15, quad = (t & 63) >> 4, w = t >> 6;
  const int wm = w >> 1, wn = w & 1;
  const int m0 = blockIdx.y * 128, n0 = blockIdx.x * 128;
  const int lrow = t >> 2;
  const int lko = (((t & 3) ^ ((t >> 3) & 3))) * 8;
  const int fsw = ((ln >> 1) & 3);
  f32x4 acc[4][4];
#pragma unroll
  for (int i = 0; i < 4; ++i)
#pragma unroll
    for (int j = 0; j < 4; ++j) acc[i][j] = (f32x4){0.f,0.f,0.f,0.f};

  for (int k0 = 0; k0 < K; k0 += 32) {
    __syncthreads();
#pragma unroll
    for (int u = 0; u < 2; ++u) {
      int row = u*64 + lrow;
      gld_lds16(Ah + (size_t)(m0+row)*K + k0 + lko, sA + u*2048 + t*8);
      gld_lds16(Al + (size_t)(m0+row)*K + k0 + lko, sA + 4096 + u*2048 + t*8);
      gld_lds16(Bh + (size_t)(n0+row)*K + k0 + lko, sB + u*2048 + t*8);
      gld_lds16(Bl + (size_t)(n0+row)*K + k0 + lko, sB + 4096 + u*2048 + t*8);
    }
    __syncthreads();
    bf16x8 ah[4], al[4], bh[4], bl[4];
#pragma unroll
    for (int mt = 0; mt < 4; ++mt) {
      int r = wm*64 + mt*16 + ln;
      ah[mt] = *(bf16x8*)&sA[r*32 + (quad ^ fsw)*8];
      al[mt] = *(bf16x8*)&sA[4096 + r*32 + (quad ^ fsw)*8];
    }
#pragma unroll
    for (int nt = 0; nt < 4; ++nt) {
      int r = wn*64 + nt*16 + ln;
      bh[nt] = *(bf16x8*)&sB[r*32 + (quad ^ fsw)*8];
      bl[nt] = *(bf16x8*)&sB[4096 + r*32 + (quad ^ fsw)*8];
    }
#pragma unroll
    for (int mt = 0; mt < 4; ++mt)
#pragma unroll
      for (int nt = 0; nt < 4; ++nt) {
        acc[mt][nt] = __builtin_amdgcn_mfma_f32_16x16x32_bf16(ah[mt], bh[nt], acc[mt][nt], 0, 0, 0);
        acc[mt][nt] = __builtin_amdgcn_mfma_f32_16x16x32_bf16(ah[mt], bl[nt], acc[mt][nt], 0, 0, 0);
        acc[mt][nt] = __builtin_amdgcn_mfma_f32_16x16x32_bf16(al[mt], bh[nt], acc[mt][nt], 0, 0, 0);
      }
  }
#pragma unroll
  for (int nt = 0; nt < 4; ++nt) {
    float bv = bias[n0 + wn*64 + nt*16 + ln] * bscale;
#pragma unroll
    for (int mt = 0; mt < 4; ++mt)
#pragma unroll
      for (int r = 0; r < 4; ++r)
        C[(size_t)(m0 + wm*64 + mt*16 + quad*4 + r)*N + (n0 + wn*64 + nt*16 + ln)] =
            acc[mt][nt][r] + bv;
  }
}

// ---------------------------------------------------------------------------
// Flash attention v3: block = (b,h) x 128 q-rows x 128-key tiles; 4 waves,
// wave w owns q rows w*32..+31 (2 q-tiles of 16 held as B-frags in regs).
// St[kc][q] = K·Q^T (per-lane softmax state, q = lane&15). All LDS tiles
// XOR-swizzled (2-way banks = free). sP 128x128 shorts overlays sQ.
// Logits in base-2 domain. Mask fast-path via per-chunk flags.
// Epilogue writes ctx hi+lo bf16 planes.
// ---------------------------------------------------------------------------
__global__ __launch_bounds__(256, 2) void attn_sp3(
    const short* __restrict__ QB, const short* __restrict__ KB,
    const short* __restrict__ VT, const float* __restrict__ mb,
    const int* __restrict__ flg,
    short* __restrict__ CTXh, short* __restrict__ CTXl)
{
  __shared__ __align__(16) short lds[32768];   // 64 KB
  short* sK = lds;            // [2 ks][128 kc][32]  16 KB
  short* sV = lds + 8192;     // [4 ksv][64 d][32]   16 KB
  short* sP = lds + 16384;    // [128 q][128 kc]     32 KB (first 16 KB = sQ)
  short* sQ = lds + 16384;    // [2 ks][128 q][32]

  const int t = threadIdx.x;
  const int ln = t & 15, quad = (t & 63) >> 4, w = t >> 6;
  const int g = blockIdx.x;
  const int chunk = g >> 3, qt128 = chunk & 15, bh = ((chunk >> 4) << 3) + (g & 7);
  const int b = bh >> 4, hd = bh & 15;
  const int fsw = ((ln >> 1) & 3);

  // stage Q once: [2][128][32], XOR-swizzled chunks
#pragma unroll
  for (int i = 0; i < 4; ++i) {
    int unit = i*256 + t;
    int ks = unit >> 9, idx = unit & 511, row = idx >> 2, c = idx & 3;
    int sw = (c ^ ((row >> 1) & 3)) * 8;
    gld_lds16(QB + (size_t)(b*SEQ + qt128*128 + row)*DIMN + hd*64 + ks*32 + sw,
              sQ + unit*8);
  }
  __syncthreads();
  bf16x8 qf[2][2];
#pragma unroll
  for (int qt = 0; qt < 2; ++qt)
#pragma unroll
    for (int ks = 0; ks < 2; ++ks) {
      int q = w*32 + qt*16 + ln;
      qf[qt][ks] = *(bf16x8*)&sQ[ks*4096 + q*32 + (quad ^ fsw)*8];
    }

  f32x4 o_acc[2][4];
#pragma unroll
  for (int qt = 0; qt < 2; ++qt)
#pragma unroll
    for (int nt = 0; nt < 4; ++nt) o_acc[qt][nt] = (f32x4){0.f,0.f,0.f,0.f};
  float m_run[2] = {-1e30f, -1e30f}, l_run[2] = {0.f, 0.f};

  for (int kt = 0; kt < SEQ/128; ++kt) {
    __syncthreads();   // all waves done with prev sK/sV
#pragma unroll
    for (int i = 0; i < 4; ++i) {
      int unit = i*256 + t;
      { int ks = unit >> 9, idx = unit & 511, row = idx >> 2, c = idx & 3;
        int sw = (c ^ ((row >> 1) & 3)) * 8;
        gld_lds16(KB + (size_t)(b*SEQ + kt*128 + row)*DIMN + hd*64 + ks*32 + sw,
                  sK + unit*8); }
      { int ksv = unit >> 8, idx = unit & 255, d = idx >> 2, c = idx & 3;
        int sw = (c ^ ((d >> 1) & 3)) * 8;
        gld_lds16(VT + ((size_t)bh*64 + d)*SEQ + kt*128 + ksv*32 + sw,
                  sV + unit*8); }
    }
    __syncthreads();

    // St[kc 128][q 32 per wave] = K·Q^T
    f32x4 sacc[8][2];
#pragma unroll
    for (int mt = 0; mt < 8; ++mt)
#pragma unroll
      for (int qt = 0; qt < 2; ++qt) sacc[mt][qt] = (f32x4){0.f,0.f,0.f,0.f};
#pragma unroll
    for (int ks = 0; ks < 2; ++ks)
#pragma unroll
      for (int mt = 0; mt < 8; ++mt) {
        bf16x8 kf = *(bf16x8*)&sK[ks*4096 + (mt*16 + ln)*32 + (quad ^ fsw)*8];
        sacc[mt][0] = __builtin_amdgcn_mfma_f32_16x16x32_bf16(kf, qf[0][ks], sacc[mt][0], 0, 0, 0);
        sacc[mt][1] = __builtin_amdgcn_mfma_f32_16x16x32_bf16(kf, qf[1][ks], sacc[mt][1], 0, 0, 0);
      }

    // mask bias (slow path only)
    bool allv = flg[b*16 + kt] != 0;
    if (!allv) {
#pragma unroll
      for (int mt = 0; mt < 8; ++mt) {
        fvec4 m4 = *(const fvec4*)&mb[b*SEQ + kt*128 + mt*16 + quad*4];
#pragma unroll
        for (int qt = 0; qt < 2; ++qt)
#pragma unroll
          for (int r = 0; r < 4; ++r) sacc[mt][qt][r] += m4[r];
      }
    }

    // online softmax per q-tile (lane owns q = w*32+qt*16+ln)
    float alpha[2];
#pragma unroll
    for (int qt = 0; qt < 2; ++qt) {
      float tmax = -1e30f;
#pragma unroll
      for (int mt = 0; mt < 8; ++mt)
#pragma unroll
        for (int r = 0; r < 4; ++r) tmax = fmaxf(tmax, sacc[mt][qt][r]);
      tmax = fmaxf(tmax, __shfl_xor(tmax, 16));
      tmax = fmaxf(tmax, __shfl_xor(tmax, 32));
      float mnew = fmaxf(m_run[qt], tmax);
      alpha[qt] = exp2f(m_run[qt] - mnew);
      m_run[qt] = mnew;
      float rs = 0.f;
      const int q = w*32 + qt*16 + ln;
#pragma unroll
      for (int mt = 0; mt < 8; ++mt) {
        s16x4 ph;
#pragma unroll
        for (int r = 0; r < 4; ++r) {
          float p = exp2f(sacc[mt][qt][r] - mnew);
          rs += p;
          ph[r] = f2bf(p);
        }
        int phys = (mt*2 + (quad >> 1)) ^ ln;
        *(s16x4*)&sP[q*128 + phys*8 + (quad & 1)*4] = ph;
      }
      rs += __shfl_xor(rs, 16);
      rs += __shfl_xor(rs, 32);
      l_run[qt] = l_run[qt]*alpha[qt] + rs;
    }

    // rescale O (row q' = quad*4+r; alpha uniform across quads for same ln)
#pragma unroll
    for (int qt = 0; qt < 2; ++qt) {
      float a4[4];
#pragma unroll
      for (int r = 0; r < 4; ++r) a4[r] = __shfl(alpha[qt], quad*4 + r);
#pragma unroll
      for (int nt = 0; nt < 4; ++nt)
#pragma unroll
        for (int r = 0; r < 4; ++r) o_acc[qt][nt][r] *= a4[r];
    }

    // O += P·V  (sP rows are wave-private: no barrier needed)
#pragma unroll
    for (int ksv = 0; ksv < 4; ++ksv) {
      bf16x8 vf[4];
#pragma unroll
      for (int nt = 0; nt < 4; ++nt)
        vf[nt] = *(bf16x8*)&sV[ksv*2048 + (nt*16 + ln)*32 + (quad ^ fsw)*8];
#pragma unroll
      for (int qt = 0; qt < 2; ++qt) {
        const int q = w*32 + qt*16 + ln;
        bf16x8 pf = *(bf16x8*)&sP[q*128 + ((ksv*4 + quad) ^ ln)*8];
#pragma unroll
        for (int nt = 0; nt < 4; ++nt)
          o_acc[qt][nt] = __builtin_amdgcn_mfma_f32_16x16x32_bf16(pf, vf[nt], o_acc[qt][nt], 0, 0, 0);
      }
    }
  }

  // epilogue
#pragma unroll
  for (int qt = 0; qt < 2; ++qt) {
    float invl = (l_run[qt] > 0.f) ? 1.f / l_run[qt] : 0.f;
    float i4[4];
#pragma unroll
    for (int r = 0; r < 4; ++r) i4[r] = __shfl(invl, quad*4 + r);
#pragma unroll
    for (int nt = 0; nt < 4; ++nt)
#pragma unroll
      for (int r = 0; r < 4; ++r) {
        int qrow = qt128*128 + w*32 + qt*16 + quad*4 + r;
        size_t idx = (size_t)(b*SEQ + qrow)*DIMN + hd*64 + nt*16 + ln;
        float val = o_acc[qt][nt][r] * i4[r];
        short hb = f2bf(val);
        CTXh[idx] = hb;
        CTXl[idx] = f2bf(val - bf2f(hb));
      }
  }
}

// ===========================================================================
// Fallback fp32 path for small ws_size.
// ===========================================================================
__global__ __launch_bounds__(256) void gemm_bt(
    const float* __restrict__ X, const float* __restrict__ W,
    const float* __restrict__ bias, float* __restrict__ C,
    int M, int N, int K)
{
  __shared__ __align__(16) float Xs[16][68];
  __shared__ __align__(16) float Ws[16][68];
  const int t  = threadIdx.x;
  const int tx = t & 15, ty = t >> 4;
  const int m0 = blockIdx.y << 6, n0 = blockIdx.x << 6;
  const int ldr = t >> 2;
  const int lk  = (t & 3) << 2;
  float acc[4][4] = {{0.f}};
  const float* Xp = X + (size_t)(m0 + ldr) * K + lk;
  const float* Wp = W + (size_t)(n0 + ldr) * K + lk;
  for (int k0 = 0; k0 < K; k0 += 16) {
    float4 xa = *(const float4*)(Xp + k0);
    float4 wa = *(const float4*)(Wp + k0);
    Xs[lk+0][ldr]=xa.x; Xs[lk+1][ldr]=xa.y; Xs[lk+2][ldr]=xa.z; Xs[lk+3][ldr]=xa.w;
    Ws[lk+0][ldr]=wa.x; Ws[lk+1][ldr]=wa.y; Ws[lk+2][ldr]=wa.z; Ws[lk+3][ldr]=wa.w;
    __syncthreads();
#pragma unroll
    for (int kk = 0; kk < 16; ++kk) {
      float4 a4 = *(const float4*)&Xs[kk][ty<<2];
      float4 b4 = *(const float4*)&Ws[kk][tx<<2];
      float av[4] = {a4.x, a4.y, a4.z, a4.w};
      float bv[4] = {b4.x, b4.y, b4.z, b4.w};
#pragma unroll
      for (int i = 0; i < 4; ++i)
#pragma unroll
        for (int j = 0; j < 4; ++j)
          acc[i][j] = fmaf(av[i], bv[j], acc[i][j]);
    }
    __syncthreads();
  }
  float4 bb4 = *(const float4*)&bias[n0 + (tx<<2)];
  const float bv[4] = {bb4.x, bb4.y, bb4.z, bb4.w};
#pragma unroll
  for (int i = 0; i < 4; ++i) {
    float4 o;
    o.x = acc[i][0]+bv[0]; o.y = acc[i][1]+bv[1];
    o.z = acc[i][2]+bv[2]; o.w = acc[i][3]+bv[3];
    *(float4*)&C[(size_t)(m0 + (ty<<2) + i) * N + n0 + (tx<<2)] = o;
  }
}

__global__ __launch_bounds__(256) void attn_fwd(
    const float* __restrict__ Q, const float* __restrict__ Kbuf,
    const float* __restrict__ Vbuf, const int* __restrict__ mask,
    float* __restrict__ CTX)
{
  __shared__ __align__(16) float Qs[64][68];
  __shared__ __align__(16) float KPs[64][68];
  __shared__ __align__(16) float Vs[64][68];
  const int t  = threadIdx.x;
  const int tx = t & 15, ty = t >> 4;
  const int qt = blockIdx.x;
  const int bh = blockIdx.y;
  const int b  = bh >> 4, h = bh & 15;
  const int ldr = t >> 2;
  const int lcb = (t & 3) << 2;
  const float* Qp = Q + (size_t)(b*SEQ + (qt<<6)) * DIMN + h*DHEAD;
#pragma unroll
  for (int u = 0; u < 4; ++u) {
    int kb = lcb + (u<<4);
    float4 q4 = *(const float4*)(Qp + (size_t)ldr*DIMN + kb);
    Qs[kb+0][ldr]=q4.x; Qs[kb+1][ldr]=q4.y; Qs[kb+2][ldr]=q4.z; Qs[kb+3][ldr]=q4.w;
  }
  float mrow[4], lsum[4], o[4][4];
#pragma unroll
  for (int i = 0; i < 4; ++i) {
    mrow[i] = -1e30f; lsum[i] = 0.f;
#pragma unroll
    for (int j = 0; j < 4; ++j) o[i][j] = 0.f;
  }
  const int qrow0 = ty << 2;
  const int col0  = tx << 2;
  for (int kt = 0; kt < SEQ/64; ++kt) {
    __syncthreads();
    const float* Kp = Kbuf + (size_t)(b*SEQ + (kt<<6)) * DIMN + h*DHEAD;
    const float* Vp = Vbuf + (size_t)(b*SEQ + (kt<<6)) * DIMN + h*DHEAD;
#pragma unroll
    for (int u = 0; u < 4; ++u) {
      int kb = lcb + (u<<4);
      float4 k4 = *(const float4*)(Kp + (size_t)ldr*DIMN + kb);
      KPs[kb+0][ldr]=k4.x; KPs[kb+1][ldr]=k4.y; KPs[kb+2][ldr]=k4.z; KPs[kb+3][ldr]=k4.w;
      float4 v4 = *(const float4*)(Vp + (size_t)ldr*DIMN + kb);
      *(float4*)&Vs[ldr][kb] = v4;
    }
    __syncthreads();
    float s[4][4] = {{0.f}};
#pragma unroll 8
    for (int kk = 0; kk < 64; ++kk) {
      float4 a4 = *(const float4*)&Qs[kk][qrow0];
      float4 b4 = *(const float4*)&KPs[kk][col0];
      float av[4] = {a4.x, a4.y, a4.z, a4.w};
      float bv[4] = {b4.x, b4.y, b4.z, b4.w};
#pragma unroll
      for (int i = 0; i < 4; ++i)
#pragma unroll
        for (int j = 0; j < 4; ++j)
          s[i][j] = fmaf(av[i], bv[j], s[i][j]);
    }
    int mk[4];
#pragma unroll
    for (int j = 0; j < 4; ++j) mk[j] = mask[b*SEQ + (kt<<6) + col0 + j];
    float p[4][4];
#pragma unroll
    for (int i = 0; i < 4; ++i) {
#pragma unroll
      for (int j = 0; j < 4; ++j)
        s[i][j] = mk[j] ? s[i][j]*0.125f : -1e30f;
      float tm = fmaxf(fmaxf(s[i][0], s[i][1]), fmaxf(s[i][2], s[i][3]));
#pragma unroll
      for (int off = 8; off >= 1; off >>= 1)
        tm = fmaxf(tm, __shfl_xor(tm, off, 64));
      float mnew  = fmaxf(mrow[i], tm);
      float aa = __expf(mrow[i] - mnew);
      mrow[i] = mnew;
      float rsum = 0.f;
#pragma unroll
      for (int j = 0; j < 4; ++j) {
        float pv = __expf(s[i][j] - mnew);
        p[i][j] = pv; rsum += pv;
      }
#pragma unroll
      for (int off = 8; off >= 1; off >>= 1)
        rsum += __shfl_xor(rsum, off, 64);
      lsum[i] = lsum[i]*aa + rsum;
#pragma unroll
      for (int j = 0; j < 4; ++j) o[i][j] *= aa;
    }
    __syncthreads();
#pragma unroll
    for (int i = 0; i < 4; ++i)
#pragma unroll
      for (int j = 0; j < 4; ++j)
        KPs[col0 + j][qrow0 + i] = p[i][j];
    __syncthreads();
#pragma unroll 8
    for (int kk = 0; kk < 64; ++kk) {
      float4 a4 = *(const float4*)&KPs[kk][qrow0];
      float4 v4 = *(const float4*)&Vs[kk][col0];
      float av[4] = {a4.x, a4.y, a4.z, a4.w};
      float vv[4] = {v4.x, v4.y, v4.z, v4.w};
#pragma unroll
      for (int i = 0; i < 4; ++i)
#pragma unroll
        for (int j = 0; j < 4; ++j)
          o[i][j] = fmaf(av[i], vv[j], o[i][j]);
    }
  }
  float* Cp = CTX + (size_t)(b*SEQ + (qt<<6)) * DIMN + h*DHEAD;
#pragma unroll
  for (int i = 0; i < 4; ++i) {
    float inv = lsum[i] > 0.f ? 1.0f/lsum[i] : 0.f;
    float4 ov;
    ov.x = o[i][0]*inv; ov.y = o[i][1]*inv;
    ov.z = o[i][2]*inv; ov.w = o[i][3]*inv;
    *(float4*)(Cp + (size_t)(qrow0 + i)*DIMN + col0) = ov;
  }
}

// ---------------------------------------------------------------------------
extern "C" void kernel_launch(void* const* d_in, const int* in_sizes, int n_in,
                              void* d_out, int out_size, void* d_ws, size_t ws_size,
                              hipStream_t stream)
{
  const float* query = (const float*)d_in[0];
  const float* key   = (const float*)d_in[1];
  const float* value = (const float*)d_in[2];
  const int*   mask  = (const int*)d_in[3];
  const float* Wq = (const float*)d_in[4];
  const float* bq = (const float*)d_in[5];
  const float* Wk = (const float*)d_in[6];
  const float* bk = (const float*)d_in[7];
  const float* Wv = (const float*)d_in[8];
  const float* bv = (const float*)d_in[9];
  const float* Wo = (const float*)d_in[10];
  const float* bo = (const float*)d_in[11];
  float* out = (float*)d_out;

  const size_t E  = (size_t)MROWS * DIMN;   // 8,388,608
  const size_t WE = (size_t)DIMN * DIMN;    // 1,048,576

  // ws layout (bytes)
  const size_t o_XB   = 5*WE*2;                 // weights: 10 MB
  const size_t o_QB   = o_XB   + 3*E*2;         // XBq,XBk,XBv: 48 MB
  const size_t o_KB   = o_QB   + E*2;
  const size_t o_VT   = o_KB   + E*2;
  const size_t o_CTXh = o_VT   + E*2;
  const size_t o_CTXl = o_CTXh + E*2;
  const size_t o_MB   = o_CTXl + E*2;
  const size_t o_FLG  = o_MB   + MROWS*4;
  const size_t NEED   = o_FLG  + 64*4;          // ~138 MB

  if (ws_size < NEED) {
    const size_t n = E;
    float* Qb = (float*)d_ws;
    float* Kb = Qb + n;
    float* Vb = Kb + n;
    float* Cb = Vb + n;
    dim3 gg(DIMN/64, MROWS/64), blk(256);
    hipLaunchKernelGGL(gemm_bt, gg, blk, 0, stream, query, Wq, bq, Qb, MROWS, DIMN, DIMN);
    hipLaunchKernelGGL(gemm_bt, gg, blk, 0, stream, key,   Wk, bk, Kb, MROWS, DIMN, DIMN);
    hipLaunchKernelGGL(gemm_bt, gg, blk, 0, stream, value, Wv, bv, Vb, MROWS, DIMN, DIMN);
    dim3 ga(SEQ/64, BSZ*NHEAD);
    hipLaunchKernelGGL(attn_fwd, ga, blk, 0, stream, Qb, Kb, Vb, mask, Cb);
    hipLaunchKernelGGL(gemm_bt, gg, blk, 0, stream, Cb, Wo, bo, out, MROWS, DIMN, DIMN);
    return;
  }

  char* Wp = (char*)d_ws;
  short* WQh = (short*)Wp;
  short* WKh = WQh + WE;
  short* WVh = WQh + 2*WE;
  short* WOh = WQh + 3*WE;
  short* WOl = WQh + 4*WE;
  short* XBq  = (short*)(Wp + o_XB);
  short* XBk  = XBq + E;
  short* XBv  = XBk + E;
  short* QB   = (short*)(Wp + o_QB);
  short* KB   = (short*)(Wp + o_KB);
  short* VT   = (short*)(Wp + o_VT);
  short* CTXh = (short*)(Wp + o_CTXh);
  short* CTXl = (short*)(Wp + o_CTXl);
  float* MB   = (float*)(Wp + o_MB);
  int*   FLG  = (int*)(Wp + o_FLG);

  dim3 blk(256);
  dim3 gW(WE/1024, 4), gX(E/1024, 3);
  dim3 gg(DIMN/128, MROWS/128);       // (8, 64)
  dim3 gat(BSZ*NHEAD*SEQ/128);        // 1024

  hipLaunchKernelGGL(pack_w4, gW, blk, 0, stream, Wq, Wk, Wv, Wo,
                     WQh, WKh, WVh, WOh, WOl, (long)WE);
  hipLaunchKernelGGL(maskbias_k, dim3(MROWS/256), blk, 0, stream, mask, MB, MROWS);
  hipLaunchKernelGGL(mask_flags, dim3(64), dim3(64), 0, stream, mask, FLG);
  hipLaunchKernelGGL(pack_hi3, gX, blk, 0, stream, query, key, value,
                     XBq, XBk, XBv, (long)E);

  hipLaunchKernelGGL(gemm_h, gg, blk, 0, stream, XBq, WQh, bq, QSC,
                     (float*)nullptr, QB, MROWS, DIMN, DIMN, 1);
  hipLaunchKernelGGL(gemm_h, gg, blk, 0, stream, XBk, WKh, bk, 1.f,
                     (float*)nullptr, KB, MROWS, DIMN, DIMN, 1);
  hipLaunchKernelGGL(gemm_h, gg, blk, 0, stream, XBv, WVh, bv, 1.f,
                     (float*)nullptr, VT, MROWS, DIMN, DIMN, 2);

  hipLaunchKernelGGL(attn_sp3, gat, blk, 0, stream, QB, KB, VT, MB, FLG, CTXh, CTXl);

  hipLaunchKernelGGL(gemm_sp, gg, blk, 0, stream, CTXh, CTXl, WOh, WOl, bo, 1.f,
                     out, MROWS, DIMN, DIMN);
}